// Round 2
// baseline (1612.278 us; speedup 1.0000x reference)
//
#include <hip/hip_runtime.h>

typedef unsigned short u16;
typedef unsigned int   u32;

#define BT   4096
#define TSEQ 64
#define NB   64

__device__ __forceinline__ float bf(u16 v) {
    u32 u = ((u32)v) << 16;
    return __builtin_bit_cast(float, u);
}
__device__ __forceinline__ u16 f2b(float f) {
    u32 u = __builtin_bit_cast(u32, f);
    return (u16)((u + 0x7fffu + ((u >> 16) & 1u)) >> 16);  // RNE
}
__device__ __forceinline__ float lrelu(float x) { return x > 0.f ? x : 0.2f * x; }

#define NSEG 22
struct Segs { const void* src[NSEG]; int off[NSEG + 1]; int size[NSEG]; };

// ---- dtype sniff on lstm_k (N(0,0.05)): bf16 -> all exponents in [100,130];
// fp32 -> even u16 indices are random mantissa bits (~12% pass). Also zeros scal.
__global__ void sniff_kernel(const u16* __restrict__ probe, int* __restrict__ flag,
                             float* __restrict__ scal) {
    __shared__ int cnt[4];
    const int tid = threadIdx.x;
    int c = 0;
    for (int i = tid; i < 2048; i += 256) {
        u16 v = probe[2 * i];
        int e = (v >> 7) & 0xFF;
        if (v == 0 || (e >= 100 && e <= 130)) c++;
    }
    for (int off = 32; off; off >>= 1) c += __shfl_down(c, off, 64);
    if ((tid & 63) == 0) cnt[tid >> 6] = c;
    __syncthreads();
    if (tid == 0) {
        int t = cnt[0] + cnt[1] + cnt[2] + cnt[3];
        *flag = (t < 1024) ? 1 : 0;   // 1 = inputs are fp32
    }
    if (tid < 32) scal[tid] = 0.f;
}

// ---- canonicalize all float tensors into an fp32 arena ----
__global__ __launch_bounds__(256) void convert_kernel(Segs S, const int* __restrict__ flag,
                                                      float* __restrict__ arena) {
    const int gid = blockIdx.x * 256 + threadIdx.x;
    if (gid >= S.off[NSEG]) return;
    const int f32 = *flag;
    int s = 0;
    while (gid >= S.off[s + 1]) s++;
    const int i = gid - S.off[s];
    float v = 0.f;
    if (i < S.size[s])
        v = f32 ? ((const float*)S.src[s])[i] : bf(((const u16*)S.src[s])[i]);
    arena[gid] = v;
}

// ---- fused conv stack: one block per image ----
__global__ __launch_bounds__(128) void conv_kernel(
    const float* __restrict__ x,
    const float* __restrict__ W1, const float* __restrict__ b1,
    const float* __restrict__ W2, const float* __restrict__ b2,
    const float* __restrict__ W3, const float* __restrict__ b3,
    const float* __restrict__ W4, const float* __restrict__ b4,
    float* __restrict__ feat)
{
    __shared__ float xs[832];   // 13*8*8
    __shared__ float c1[384];   // 6*4*16
    __shared__ float c2[480];   // 5*3*32
    __shared__ float c3[128];   // 2*1*64
    const int bt = blockIdx.x, tid = threadIdx.x;

    for (int i = tid; i < 832; i += 128) xs[i] = x[bt * 832 + i];
    __syncthreads();

    // conv1: 2x2 s2, (13,8,8) -> (6,4,16)
    for (int idx = tid; idx < 384; idx += 128) {
        int oc = idx & 15, ow = (idx >> 4) & 3, oh = idx >> 6;
        float acc = b1[oc];
        for (int kh = 0; kh < 2; kh++)
            for (int kw = 0; kw < 2; kw++) {
                const float* xp = &xs[(2 * oh + kh) * 64 + (2 * ow + kw) * 8];
                const float* wp = &W1[((kh * 2 + kw) * 8) * 16 + oc];
                for (int ic = 0; ic < 8; ic++) acc += xp[ic] * wp[ic * 16];
            }
        c1[idx] = lrelu(acc);
    }
    __syncthreads();

    // conv2: 2x2 s1, (6,4,16) -> (5,3,32)
    for (int idx = tid; idx < 480; idx += 128) {
        int oc = idx & 31, ow = (idx >> 5) % 3, oh = idx / 96;
        float acc = b2[oc];
        for (int kh = 0; kh < 2; kh++)
            for (int kw = 0; kw < 2; kw++) {
                const float* ip = &c1[((oh + kh) * 4 + (ow + kw)) * 16];
                const float* wp = &W2[((kh * 2 + kw) * 16) * 32 + oc];
                for (int ic = 0; ic < 16; ic++) acc += ip[ic] * wp[ic * 32];
            }
        c2[idx] = lrelu(acc);
    }
    __syncthreads();

    // conv3: 2x2 s2, (5,3,32) -> (2,1,64)
    for (int idx = tid; idx < 128; idx += 128) {
        int oc = idx & 63, oh = idx >> 6;
        float acc = b3[oc];
        for (int kh = 0; kh < 2; kh++)
            for (int kw = 0; kw < 2; kw++) {
                const float* ip = &c2[((2 * oh + kh) * 3 + kw) * 32];
                const float* wp = &W3[((kh * 2 + kw) * 32) * 64 + oc];
                for (int ic = 0; ic < 32; ic++) acc += ip[ic] * wp[ic * 64];
            }
        c3[idx] = lrelu(acc);
    }
    __syncthreads();

    // conv4 1x1, (2,1,64) -> (2,1,128); keras channels_first flatten: feat[bt][oc*2+oh]
    for (int idx = tid; idx < 256; idx += 128) {
        int oh = idx & 1, oc = idx >> 1;
        float acc = b4[oc];
        const float* ip = &c3[oh * 64];
        for (int ic = 0; ic < 64; ic++) acc += ip[ic] * W4[ic * 128 + oc];
        feat[bt * 256 + idx] = lrelu(acc);
    }
}

// ---- pack Wr (256,1024) fp32 -> bf16 P[k/4][1024][4] for ushort4 LSTM loads ----
__global__ void pack_wr_kernel(const float* __restrict__ Wr, u16* __restrict__ P) {
    int i = blockIdx.x * 256 + threadIdx.x;   // 262144 elems
    int k = i >> 10, j = i & 1023;
    P[(((k >> 2) << 10) + j) * 4 + (k & 3)] = f2b(Wr[i]);
}

// ---- zx = feat @ lstm_k + lstm_b : (4096,256)x(256,1024) ----
__global__ __launch_bounds__(256) void zx_kernel(
    const float* __restrict__ feat, const float* __restrict__ Wk,
    const float* __restrict__ bias, float* __restrict__ zx)
{
    __shared__ __align__(16) float fa[16 * 256];
    const int r0 = blockIdx.y * 16;
    const int j = blockIdx.x * 256 + threadIdx.x;
    for (int i = threadIdx.x; i < 4096; i += 256) fa[i] = feat[r0 * 256 + i];
    __syncthreads();

    float acc[16];
    const float bj = bias[j];
#pragma unroll
    for (int r = 0; r < 16; r++) acc[r] = bj;
    for (int k4 = 0; k4 < 64; k4++) {
        float w0 = Wk[(4 * k4 + 0) * 1024 + j];
        float w1 = Wk[(4 * k4 + 1) * 1024 + j];
        float w2 = Wk[(4 * k4 + 2) * 1024 + j];
        float w3 = Wk[(4 * k4 + 3) * 1024 + j];
#pragma unroll
        for (int r = 0; r < 16; r++) {
            float4 h4 = *(const float4*)&fa[r * 256 + 4 * k4];
            acc[r] += h4.x * w0 + h4.y * w1 + h4.z * w2 + h4.w * w3;
        }
    }
#pragma unroll
    for (int r = 0; r < 16; r++) zx[(size_t)(r0 + r) * 1024 + j] = acc[r];
}

// ---- LSTM: one block per batch element ----
__global__ __launch_bounds__(256) void lstm_kernel(
    const float* __restrict__ zx, const u16* __restrict__ P,
    float* __restrict__ hseq)
{
    __shared__ __align__(16) float hs[256];
    const int b = blockIdx.x, u = threadIdx.x;
    hs[u] = 0.f;
    float c = 0.f;
    __syncthreads();
    const ushort4* P4 = (const ushort4*)P;

    for (int t = 0; t < TSEQ; t++) {
        const float* zr = &zx[(size_t)(b * TSEQ + t) * 1024];
        float ai = zr[u], af = zr[256 + u], ag = zr[512 + u], ao = zr[768 + u];
        for (int k4 = 0; k4 < 64; k4++) {
            float4 h4 = *(const float4*)&hs[4 * k4];
            ushort4 wi = P4[k4 * 1024 + u];
            ushort4 wf = P4[k4 * 1024 + 256 + u];
            ushort4 wg = P4[k4 * 1024 + 512 + u];
            ushort4 wo = P4[k4 * 1024 + 768 + u];
            ai += h4.x * bf(wi.x) + h4.y * bf(wi.y) + h4.z * bf(wi.z) + h4.w * bf(wi.w);
            af += h4.x * bf(wf.x) + h4.y * bf(wf.y) + h4.z * bf(wf.z) + h4.w * bf(wf.w);
            ag += h4.x * bf(wg.x) + h4.y * bf(wg.y) + h4.z * bf(wg.z) + h4.w * bf(wg.w);
            ao += h4.x * bf(wo.x) + h4.y * bf(wo.y) + h4.z * bf(wo.z) + h4.w * bf(wo.w);
        }
        float ig = 1.f / (1.f + __expf(-ai));
        float fg = 1.f / (1.f + __expf(-af));
        float og = 1.f / (1.f + __expf(-ao));
        float gg = tanhf(ag);
        c = fg * c + ig * gg;
        float h = og * tanhf(c);
        __syncthreads();
        hs[u] = h;
        hseq[(size_t)(b * TSEQ + t) * 256 + u] = h;
        __syncthreads();
    }
}

// ---- pir head + vpred: one wave per row ----
__global__ __launch_bounds__(64) void pir_kernel(
    const float* __restrict__ hseq,
    const float* __restrict__ pir_W, const float* __restrict__ pir_b,
    const float* __restrict__ v_W, const float* __restrict__ v_b,
    const int* __restrict__ a_taken,
    float* __restrict__ entpir, float* __restrict__ ppira, float* __restrict__ vpred)
{
    __shared__ float hr[256];
    __shared__ float pz[36];
    const int r = blockIdx.x, tid = threadIdx.x;
    for (int i = tid; i < 256; i += 64) hr[i] = hseq[(size_t)r * 256 + i];
    __syncthreads();

    if (tid < 36) {
        float acc = pir_b[tid];
        for (int k = 0; k < 256; k++) acc += hr[k] * pir_W[k * 36 + tid];
        pz[tid] = acc;
    }
    float va = 0.f;
    for (int k = tid; k < 256; k += 64) va += hr[k] * v_W[k];
    for (int off = 32; off; off >>= 1) va += __shfl_down(va, off, 64);
    if (tid == 0) vpred[r] = va + v_b[0];
    __syncthreads();

    if (tid == 0) {
        float Z = 0.f, U = 0.f;
        for (int jj = 0; jj < 36; jj++) { float e = __expf(pz[jj]); Z += e; U += e * pz[jj]; }
        entpir[r] = logf(Z) - U / Z;
        ppira[r]  = __expf(pz[a_taken[r]]) / Z;
    }
}

// ---- pim head fused: GEMM + masked softmax + entropy, 16 rows per block ----
__global__ __launch_bounds__(256) void pim_kernel(
    const float* __restrict__ hseq,
    const float* __restrict__ pim_W, const float* __restrict__ pim_b,
    const int* __restrict__ mask, const int* __restrict__ a_taken,
    float* __restrict__ entpim, float* __restrict__ ppima)
{
    __shared__ __align__(16) float hsm[16 * 256];
    __shared__ float zt[16 * 256];
    __shared__ float redS[16][16], redU[16][16];
    __shared__ float runS[16], runU[16], za[16];
    const int r0 = blockIdx.x * 16, tid = threadIdx.x;

    for (int i = tid; i < 4096; i += 256) hsm[i] = hseq[(size_t)r0 * 256 + i];
    if (tid < 16) { runS[tid] = 0.f; runU[tid] = 0.f; }
    __syncthreads();

    for (int tile = 0; tile < 16; tile++) {
        const int j = tile * 256 + tid;
        float acc[16];
#pragma unroll
        for (int r = 0; r < 16; r++) acc[r] = 0.f;
        for (int k4 = 0; k4 < 64; k4++) {
            float w0 = pim_W[(size_t)(4 * k4 + 0) * 4096 + j];
            float w1 = pim_W[(size_t)(4 * k4 + 1) * 4096 + j];
            float w2 = pim_W[(size_t)(4 * k4 + 2) * 4096 + j];
            float w3 = pim_W[(size_t)(4 * k4 + 3) * 4096 + j];
#pragma unroll
            for (int r = 0; r < 16; r++) {
                float4 h4 = *(const float4*)&hsm[r * 256 + 4 * k4];
                acc[r] += h4.x * w0 + h4.y * w1 + h4.z * w2 + h4.w * w3;
            }
        }
        const float bj = pim_b[j];
#pragma unroll
        for (int r = 0; r < 16; r++) zt[r * 256 + tid] = acc[r] + bj;
        __syncthreads();

        const int rr = tid >> 4, l = tid & 15;
        const int arr = a_taken[r0 + rr];
        const int* mrow = &mask[(size_t)(r0 + rr) * 4096 + tile * 256];
        float S = 0.f, U = 0.f;
        for (int cidx = l; cidx < 256; cidx += 16) {
            if (mrow[cidx]) {
                float z = zt[rr * 256 + cidx];
                float e = __expf(z);
                S += e; U += e * z;
                if (tile * 256 + cidx == arr) za[rr] = z;   // a<36: tile 0 only
            }
        }
        redS[rr][l] = S; redU[rr][l] = U;
        __syncthreads();
        if (tid < 16) {
            float s = 0.f, uu = 0.f;
            for (int l2 = 0; l2 < 16; l2++) { s += redS[tid][l2]; uu += redU[tid][l2]; }
            runS[tid] += s; runU[tid] += uu;
        }
        __syncthreads();
    }
    if (tid < 16) {
        float S = runS[tid], U = runU[tid];
        entpim[r0 + tid] = logf(S) - U / S;
        ppima[r0 + tid]  = __expf(za[tid]) / S;
    }
}

// ---- GAE mean/std (population) ----
__global__ __launch_bounds__(256) void gae_kernel(const float* __restrict__ g, float* scal) {
    const int tid = threadIdx.x;
    float s = 0.f, s2 = 0.f;
    for (int i = tid; i < BT; i += 256) { float v = g[i]; s += v; s2 += v * v; }
    for (int off = 32; off; off >>= 1) { s += __shfl_down(s, off, 64); s2 += __shfl_down(s2, off, 64); }
    __shared__ float wsx[8];
    const int w = tid >> 6;
    if ((tid & 63) == 0) { wsx[w] = s; wsx[4 + w] = s2; }
    __syncthreads();
    if (tid == 0) {
        float S = 0.f, S2 = 0.f;
        for (int i = 0; i < 4; i++) { S += wsx[i]; S2 += wsx[4 + i]; }
        float mean = S / (float)BT;
        float var = S2 / (float)BT - mean * mean;
        scal[0] = mean;
        scal[1] = sqrtf(fmaxf(var, 0.f));
    }
}

// ---- pg loss + entropy sums ----
__global__ __launch_bounds__(256) void pg_kernel(
    const float* __restrict__ ppira, const float* __restrict__ ppima,
    const float* __restrict__ entpir, const float* __restrict__ entpim,
    const float* __restrict__ lgold, const float* __restrict__ gae,
    float* __restrict__ scal)
{
    const int t = blockIdx.x * 256 + threadIdx.x;
    const float mean = scal[0], sd = scal[1];
    float p  = (t & 1) ? ppima[t] : ppira[t];   // even t -> pir
    float ln = logf(p);
    float rt = __expf(ln - lgold[t]);
    float g  = (gae[t] - mean) / (sd + 1e-8f);
    float rtc = fminf(fmaxf(rt, 0.8f), 1.2f);
    float pg = fmaxf(-g * rt, -g * rtc);
    float e1 = entpir[t], e2 = entpim[t];
    for (int off = 32; off; off >>= 1) {
        pg += __shfl_down(pg, off, 64);
        e1 += __shfl_down(e1, off, 64);
        e2 += __shfl_down(e2, off, 64);
    }
    if ((threadIdx.x & 63) == 0) {
        atomicAdd(&scal[2], pg);
        atomicAdd(&scal[3], e1 + e2);
    }
}

// ---- vf loss: faithful (BT,BT) broadcast ----
__global__ __launch_bounds__(256) void vf_kernel(
    const float* __restrict__ vpred, const float* __restrict__ ovp,
    const float* __restrict__ ret, float* __restrict__ scal)
{
    const int i = blockIdx.x;
    const float vp = vpred[i];
    float s = 0.f;
    for (int j = threadIdx.x; j < BT; j += 256) {
        float r = ret[j], o = ovp[j];
        float d = fminf(fmaxf(vp - o, -0.2f), 0.2f);
        float v1 = vp - r;     v1 *= v1;
        float v2 = o + d - r;  v2 *= v2;
        s += fmaxf(v1, v2);
    }
    for (int off = 32; off; off >>= 1) s += __shfl_down(s, off, 64);
    __shared__ float wsum[4];
    if ((threadIdx.x & 63) == 0) wsum[threadIdx.x >> 6] = s;
    __syncthreads();
    if (threadIdx.x == 0) atomicAdd(&scal[5], wsum[0] + wsum[1] + wsum[2] + wsum[3]);
}

// ---- finalize (dtype-flag-aware output) ----
__global__ void fin_kernel(const float* __restrict__ scal, const int* __restrict__ flag,
                           void* __restrict__ out) {
    float pg  = scal[2] / (float)BT;
    float ent = scal[3];
    float vf  = 0.5f * scal[5] / ((float)BT * (float)BT);
    float loss = pg - ent + vf;
    if (*flag) {
        float* o = (float*)out;
        o[0] = loss; o[1] = pg; o[2] = ent; o[3] = vf;
    } else {
        u16* o = (u16*)out;
        o[0] = f2b(loss); o[1] = f2b(pg); o[2] = f2b(ent); o[3] = f2b(vf);
    }
}

extern "C" void kernel_launch(void* const* d_in, const int* in_sizes, int n_in,
                              void* d_out, int out_size, void* d_ws, size_t ws_size,
                              hipStream_t stream)
{
    const int* mask = (const int*)d_in[1];
    const int* a_tk = (const int*)d_in[3];

    // float-tensor segments in setup_inputs order (ints excluded)
    static const int sz[NSEG]  = {3407872, 4096, 4096, 4096, 4096, 512, 16, 2048, 32,
                                  8192, 64, 8192, 128, 262144, 262144, 1024,
                                  9216, 36, 1048576, 4096, 256, 1};
    static const int din[NSEG] = {0, 2, 4, 5, 6, 7, 8, 9, 10, 11, 12, 13, 14,
                                  15, 16, 17, 18, 19, 20, 21, 22, 23};
    Segs S;
    int off = 0;
    for (int s = 0; s < NSEG; s++) {
        S.src[s] = d_in[din[s]];
        S.off[s] = off;
        S.size[s] = sz[s];
        off += (sz[s] + 3) & ~3;
    }
    S.off[NSEG] = off;   // 5,030,936 floats

    float* arena = (float*)d_ws;
    const float* xa    = arena + S.off[0];
    const float* lgold = arena + S.off[1];
    const float* gae   = arena + S.off[2];
    const float* ovp   = arena + S.off[3];
    const float* ret   = arena + S.off[4];
    const float* W1 = arena + S.off[5],  *b1 = arena + S.off[6];
    const float* W2 = arena + S.off[7],  *b2 = arena + S.off[8];
    const float* W3 = arena + S.off[9],  *b3 = arena + S.off[10];
    const float* W4 = arena + S.off[11], *b4 = arena + S.off[12];
    const float* Wk = arena + S.off[13];
    const float* Wr = arena + S.off[14];
    const float* lb = arena + S.off[15];
    const float* pirW = arena + S.off[16], *pirB = arena + S.off[17];
    const float* pimW = arena + S.off[18], *pimB = arena + S.off[19];
    const float* vW   = arena + S.off[20], *vB   = arena + S.off[21];

    float* feat = arena + off;              // 1,048,576
    float* zx   = feat + 1048576;           // 4,194,304
    float* hseq = zx + 4194304;             // 1,048,576
    u16*   wrp  = (u16*)(hseq + 1048576);   // 262,144 u16 = 131,072 floats
    float* entpir = hseq + 1048576 + 131072;
    float* entpim = entpir + 4096;
    float* ppira  = entpim + 4096;
    float* ppima  = ppira + 4096;
    float* vpred  = ppima + 4096;
    float* scal   = vpred + 4096;           // 32 floats
    int*   flag   = (int*)(scal + 32);

    sniff_kernel<<<1, 256, 0, stream>>>((const u16*)d_in[15], flag, scal);
    convert_kernel<<<(S.off[NSEG] + 255) / 256, 256, 0, stream>>>(S, flag, arena);
    conv_kernel<<<BT, 128, 0, stream>>>(xa, W1, b1, W2, b2, W3, b3, W4, b4, feat);
    pack_wr_kernel<<<1024, 256, 0, stream>>>(Wr, wrp);
    zx_kernel<<<dim3(4, 256), 256, 0, stream>>>(feat, Wk, lb, zx);
    lstm_kernel<<<NB, 256, 0, stream>>>(zx, wrp, hseq);
    pir_kernel<<<BT, 64, 0, stream>>>(hseq, pirW, pirB, vW, vB, a_tk, entpir, ppira, vpred);
    pim_kernel<<<BT / 16, 256, 0, stream>>>(hseq, pimW, pimB, mask, a_tk, entpim, ppima);
    gae_kernel<<<1, 256, 0, stream>>>(gae, scal);
    pg_kernel<<<16, 256, 0, stream>>>(ppira, ppima, entpir, entpim, lgold, gae, scal);
    vf_kernel<<<BT, 256, 0, stream>>>(vpred, ovp, ret, scal);
    fin_kernel<<<1, 1, 0, stream>>>(scal, flag, (u16*)d_out);
}

// Round 3
// 1057.846 us; speedup vs baseline: 1.5241x; 1.5241x over previous
//
#include <hip/hip_runtime.h>

typedef unsigned short u16;
typedef unsigned int   u32;

#define BT   4096
#define TSEQ 64
#define NB   64

__device__ __forceinline__ float bf(u16 v) {
    u32 u = ((u32)v) << 16;
    return __builtin_bit_cast(float, u);
}
__device__ __forceinline__ u16 f2b(float f) {
    u32 u = __builtin_bit_cast(u32, f);
    return (u16)((u + 0x7fffu + ((u >> 16) & 1u)) >> 16);  // RNE
}
__device__ __forceinline__ float lrelu(float x) { return x > 0.f ? x : 0.2f * x; }

#define NSEG 22
struct Segs { const void* src[NSEG]; int off[NSEG + 1]; int size[NSEG]; };

// ---- dtype sniff on lstm_k (N(0,0.05)): bf16 -> exponents clustered; fp32 ->
// even u16 halves are random mantissa bits. Also zeros scal.
__global__ void sniff_kernel(const u16* __restrict__ probe, int* __restrict__ flag,
                             float* __restrict__ scal) {
    __shared__ int cnt[4];
    const int tid = threadIdx.x;
    int c = 0;
    for (int i = tid; i < 2048; i += 256) {
        u16 v = probe[2 * i];
        int e = (v >> 7) & 0xFF;
        if (v == 0 || (e >= 100 && e <= 130)) c++;
    }
    for (int off = 32; off; off >>= 1) c += __shfl_down(c, off, 64);
    if ((tid & 63) == 0) cnt[tid >> 6] = c;
    __syncthreads();
    if (tid == 0) {
        int t = cnt[0] + cnt[1] + cnt[2] + cnt[3];
        *flag = (t < 1024) ? 1 : 0;   // 1 = inputs are fp32
    }
    if (tid < 32) scal[tid] = 0.f;
}

// ---- canonicalize all float tensors into an fp32 arena ----
__global__ __launch_bounds__(256) void convert_kernel(Segs S, const int* __restrict__ flag,
                                                      float* __restrict__ arena) {
    const int gid = blockIdx.x * 256 + threadIdx.x;
    if (gid >= S.off[NSEG]) return;
    const int f32 = *flag;
    int s = 0;
    while (gid >= S.off[s + 1]) s++;
    const int i = gid - S.off[s];
    float v = 0.f;
    if (i < S.size[s])
        v = f32 ? ((const float*)S.src[s])[i] : bf(((const u16*)S.src[s])[i]);
    arena[gid] = v;
}

// ---- fused conv stack: one block per image ----
__global__ __launch_bounds__(128) void conv_kernel(
    const float* __restrict__ x,
    const float* __restrict__ W1, const float* __restrict__ b1,
    const float* __restrict__ W2, const float* __restrict__ b2,
    const float* __restrict__ W3, const float* __restrict__ b3,
    const float* __restrict__ W4, const float* __restrict__ b4,
    float* __restrict__ feat)
{
    __shared__ float xs[832];
    __shared__ float c1[384];
    __shared__ float c2[480];
    __shared__ float c3[128];
    const int bt = blockIdx.x, tid = threadIdx.x;

    for (int i = tid; i < 832; i += 128) xs[i] = x[bt * 832 + i];
    __syncthreads();

    for (int idx = tid; idx < 384; idx += 128) {
        int oc = idx & 15, ow = (idx >> 4) & 3, oh = idx >> 6;
        float acc = b1[oc];
        for (int kh = 0; kh < 2; kh++)
            for (int kw = 0; kw < 2; kw++) {
                const float* xp = &xs[(2 * oh + kh) * 64 + (2 * ow + kw) * 8];
                const float* wp = &W1[((kh * 2 + kw) * 8) * 16 + oc];
                for (int ic = 0; ic < 8; ic++) acc += xp[ic] * wp[ic * 16];
            }
        c1[idx] = lrelu(acc);
    }
    __syncthreads();

    for (int idx = tid; idx < 480; idx += 128) {
        int oc = idx & 31, ow = (idx >> 5) % 3, oh = idx / 96;
        float acc = b2[oc];
        for (int kh = 0; kh < 2; kh++)
            for (int kw = 0; kw < 2; kw++) {
                const float* ip = &c1[((oh + kh) * 4 + (ow + kw)) * 16];
                const float* wp = &W2[((kh * 2 + kw) * 16) * 32 + oc];
                for (int ic = 0; ic < 16; ic++) acc += ip[ic] * wp[ic * 32];
            }
        c2[idx] = lrelu(acc);
    }
    __syncthreads();

    for (int idx = tid; idx < 128; idx += 128) {
        int oc = idx & 63, oh = idx >> 6;
        float acc = b3[oc];
        for (int kh = 0; kh < 2; kh++)
            for (int kw = 0; kw < 2; kw++) {
                const float* ip = &c2[((2 * oh + kh) * 3 + kw) * 32];
                const float* wp = &W3[((kh * 2 + kw) * 32) * 64 + oc];
                for (int ic = 0; ic < 32; ic++) acc += ip[ic] * wp[ic * 64];
            }
        c3[idx] = lrelu(acc);
    }
    __syncthreads();

    for (int idx = tid; idx < 256; idx += 128) {
        int oh = idx & 1, oc = idx >> 1;
        float acc = b4[oc];
        const float* ip = &c3[oh * 64];
        for (int ic = 0; ic < 64; ic++) acc += ip[ic] * W4[ic * 128 + oc];
        feat[bt * 256 + idx] = lrelu(acc);
    }
}

// ---- pack Wr -> bf16 P[k/4][1024][4] (from native dtype) ----
__global__ void pack_wr_kernel(const void* __restrict__ Wr, const int* __restrict__ flag,
                               u16* __restrict__ P) {
    int i = blockIdx.x * 256 + threadIdx.x;   // 262144 elems
    int k = i >> 10, j = i & 1023;
    u16 v = (*flag) ? f2b(((const float*)Wr)[i]) : ((const u16*)Wr)[i];
    P[(((k >> 2) << 10) + j) * 4 + (k & 3)] = v;
}

// ---- pack pim_W -> bf16 Pw[k/4][4096][4] (from native dtype) ----
__global__ void pack_pim_kernel(const void* __restrict__ W, const int* __restrict__ flag,
                                u16* __restrict__ P) {
    int i = blockIdx.x * 256 + threadIdx.x;   // 1048576 elems
    int k = i >> 12, j = i & 4095;
    u16 v = (*flag) ? f2b(((const float*)W)[i]) : ((const u16*)W)[i];
    P[(((k >> 2) << 12) + j) * 4 + (k & 3)] = v;
}

// ---- zx = feat @ lstm_k + lstm_b : (4096,256)x(256,1024) ----
__global__ __launch_bounds__(256) void zx_kernel(
    const float* __restrict__ feat, const float* __restrict__ Wk,
    const float* __restrict__ bias, float* __restrict__ zx)
{
    __shared__ __align__(16) float fa[16 * 256];
    const int r0 = blockIdx.y * 16;
    const int j = blockIdx.x * 256 + threadIdx.x;
    for (int i = threadIdx.x; i < 4096; i += 256) fa[i] = feat[r0 * 256 + i];
    __syncthreads();

    float acc[16];
    const float bj = bias[j];
#pragma unroll
    for (int r = 0; r < 16; r++) acc[r] = bj;
    for (int k4 = 0; k4 < 64; k4++) {
        float w0 = Wk[(4 * k4 + 0) * 1024 + j];
        float w1 = Wk[(4 * k4 + 1) * 1024 + j];
        float w2 = Wk[(4 * k4 + 2) * 1024 + j];
        float w3 = Wk[(4 * k4 + 3) * 1024 + j];
#pragma unroll
        for (int r = 0; r < 16; r++) {
            float4 h4 = *(const float4*)&fa[r * 256 + 4 * k4];
            acc[r] += h4.x * w0 + h4.y * w1 + h4.z * w2 + h4.w * w3;
        }
    }
#pragma unroll
    for (int r = 0; r < 16; r++) zx[(size_t)(r0 + r) * 1024 + j] = acc[r];
}

// ---- LSTM v2: one block per batch element, 1024 threads (one per gate-unit) ----
__global__ __launch_bounds__(1024) void lstm_kernel(
    const float* __restrict__ zx, const u16* __restrict__ P,
    float* __restrict__ hseq)
{
    __shared__ __align__(16) float hs[256];
    __shared__ float zp[1024];
    const int b = blockIdx.x, tid = threadIdx.x;
    float c = 0.f;
    if (tid < 256) hs[tid] = 0.f;
    __syncthreads();
    const ushort4* P4 = (const ushort4*)P;

    for (int t = 0; t < TSEQ; t++) {
        float acc = zx[(size_t)(b * TSEQ + t) * 1024 + tid];
#pragma unroll 8
        for (int k4 = 0; k4 < 64; k4++) {
            float4 h4 = *(const float4*)&hs[4 * k4];
            ushort4 w = P4[k4 * 1024 + tid];
            acc += h4.x * bf(w.x) + h4.y * bf(w.y) + h4.z * bf(w.z) + h4.w * bf(w.w);
        }
        zp[tid] = acc;
        __syncthreads();           // gates ready; all hs reads done
        if (tid < 256) {
            float ai = zp[tid], af = zp[256 + tid], ag = zp[512 + tid], ao = zp[768 + tid];
            float ig = 1.f / (1.f + __expf(-ai));
            float fg = 1.f / (1.f + __expf(-af));
            float og = 1.f / (1.f + __expf(-ao));
            float gg = tanhf(ag);
            c = fg * c + ig * gg;
            float h = og * tanhf(c);
            hs[tid] = h;
            hseq[(size_t)(b * TSEQ + t) * 256 + tid] = h;
        }
        __syncthreads();           // new hs visible
    }
}

// ---- pir head + vpred: one wave per row ----
__global__ __launch_bounds__(64) void pir_kernel(
    const float* __restrict__ hseq,
    const float* __restrict__ pir_W, const float* __restrict__ pir_b,
    const float* __restrict__ v_W, const float* __restrict__ v_b,
    const int* __restrict__ a_taken,
    float* __restrict__ entpir, float* __restrict__ ppira, float* __restrict__ vpred)
{
    __shared__ float hr[256];
    __shared__ float pz[36];
    const int r = blockIdx.x, tid = threadIdx.x;
    for (int i = tid; i < 256; i += 64) hr[i] = hseq[(size_t)r * 256 + i];
    __syncthreads();

    if (tid < 36) {
        float acc = pir_b[tid];
        for (int k = 0; k < 256; k++) acc += hr[k] * pir_W[k * 36 + tid];
        pz[tid] = acc;
    }
    float va = 0.f;
    for (int k = tid; k < 256; k += 64) va += hr[k] * v_W[k];
    for (int off = 32; off; off >>= 1) va += __shfl_down(va, off, 64);
    if (tid == 0) vpred[r] = va + v_b[0];
    __syncthreads();

    if (tid == 0) {
        float Z = 0.f, U = 0.f;
        for (int jj = 0; jj < 36; jj++) { float e = __expf(pz[jj]); Z += e; U += e * pz[jj]; }
        entpir[r] = logf(Z) - U / Z;
        ppira[r]  = __expf(pz[a_taken[r]]) / Z;
    }
}

// ---- pim v2: grid (16 coltiles, 256 rowgroups); no zt round-trip, no atomics ----
__global__ __launch_bounds__(256) void pim_kernel(
    const float* __restrict__ hseq, const u16* __restrict__ Pw,
    const float* __restrict__ pim_b,
    const int* __restrict__ mask, const int* __restrict__ a_taken,
    float* __restrict__ partS, float* __restrict__ partU, float* __restrict__ za)
{
    __shared__ __align__(16) float hsm[16 * 256];
    __shared__ float redS[16][4], redU[16][4];
    const int tile = blockIdx.x, r0 = blockIdx.y * 16, tid = threadIdx.x;
    const int j = tile * 256 + tid;
    const int wave = tid >> 6, lane = tid & 63;

    for (int i = tid; i < 4096; i += 256) hsm[i] = hseq[(size_t)r0 * 256 + i];
    __syncthreads();

    float acc[16];
#pragma unroll
    for (int r = 0; r < 16; r++) acc[r] = 0.f;
    const ushort4* P4 = (const ushort4*)Pw;
    for (int k4 = 0; k4 < 64; k4++) {
        ushort4 w = P4[k4 * 4096 + j];
        float w0 = bf(w.x), w1 = bf(w.y), w2 = bf(w.z), w3 = bf(w.w);
#pragma unroll
        for (int r = 0; r < 16; r++) {
            float4 h4 = *(const float4*)&hsm[r * 256 + 4 * k4];
            acc[r] += h4.x * w0 + h4.y * w1 + h4.z * w2 + h4.w * w3;
        }
    }
    const float bj = pim_b[j];

    float sv[16], uv[16];
#pragma unroll
    for (int r = 0; r < 16; r++) {
        float z = acc[r] + bj;
        int m = mask[(size_t)(r0 + r) * 4096 + j];
        float e = __expf(z);
        sv[r] = m ? e : 0.f;
        uv[r] = m ? e * z : 0.f;
        if (j == a_taken[r0 + r]) za[r0 + r] = z;   // single writer (tile 0)
    }
#pragma unroll
    for (int r = 0; r < 16; r++) {
        float s = sv[r], u = uv[r];
        for (int off = 1; off < 64; off <<= 1) {
            s += __shfl_xor(s, off, 64);
            u += __shfl_xor(u, off, 64);
        }
        if (lane == 0) { redS[r][wave] = s; redU[r][wave] = u; }
    }
    __syncthreads();
    if (tid < 16) {
        float S = redS[tid][0] + redS[tid][1] + redS[tid][2] + redS[tid][3];
        float U = redU[tid][0] + redU[tid][1] + redU[tid][2] + redU[tid][3];
        partS[(size_t)tile * 4096 + r0 + tid] = S;
        partU[(size_t)tile * 4096 + r0 + tid] = U;
    }
}

// ---- fold pim partials -> entropy + p[a] ----
__global__ __launch_bounds__(256) void pimfin_kernel(
    const float* __restrict__ partS, const float* __restrict__ partU,
    const float* __restrict__ za,
    float* __restrict__ entpim, float* __restrict__ ppima)
{
    const int r = blockIdx.x * 256 + threadIdx.x;
    float S = 0.f, U = 0.f;
#pragma unroll
    for (int t = 0; t < 16; t++) { S += partS[t * 4096 + r]; U += partU[t * 4096 + r]; }
    entpim[r] = logf(S) - U / S;
    ppima[r]  = __expf(za[r]) / S;
}

// ---- GAE mean/std (population) ----
__global__ __launch_bounds__(256) void gae_kernel(const float* __restrict__ g, float* scal) {
    const int tid = threadIdx.x;
    float s = 0.f, s2 = 0.f;
    for (int i = tid; i < BT; i += 256) { float v = g[i]; s += v; s2 += v * v; }
    for (int off = 32; off; off >>= 1) { s += __shfl_down(s, off, 64); s2 += __shfl_down(s2, off, 64); }
    __shared__ float wsx[8];
    const int w = tid >> 6;
    if ((tid & 63) == 0) { wsx[w] = s; wsx[4 + w] = s2; }
    __syncthreads();
    if (tid == 0) {
        float S = 0.f, S2 = 0.f;
        for (int i = 0; i < 4; i++) { S += wsx[i]; S2 += wsx[4 + i]; }
        float mean = S / (float)BT;
        float var = S2 / (float)BT - mean * mean;
        scal[0] = mean;
        scal[1] = sqrtf(fmaxf(var, 0.f));
    }
}

// ---- pg loss + entropy sums ----
__global__ __launch_bounds__(256) void pg_kernel(
    const float* __restrict__ ppira, const float* __restrict__ ppima,
    const float* __restrict__ entpir, const float* __restrict__ entpim,
    const float* __restrict__ lgold, const float* __restrict__ gae,
    float* __restrict__ scal)
{
    const int t = blockIdx.x * 256 + threadIdx.x;
    const float mean = scal[0], sd = scal[1];
    float p  = (t & 1) ? ppima[t] : ppira[t];   // even t -> pir
    float ln = logf(p);
    float rt = __expf(ln - lgold[t]);
    float g  = (gae[t] - mean) / (sd + 1e-8f);
    float rtc = fminf(fmaxf(rt, 0.8f), 1.2f);
    float pg = fmaxf(-g * rt, -g * rtc);
    float e1 = entpir[t], e2 = entpim[t];
    for (int off = 32; off; off >>= 1) {
        pg += __shfl_down(pg, off, 64);
        e1 += __shfl_down(e1, off, 64);
        e2 += __shfl_down(e2, off, 64);
    }
    if ((threadIdx.x & 63) == 0) {
        atomicAdd(&scal[2], pg);
        atomicAdd(&scal[3], e1 + e2);
    }
}

// ---- vf loss: faithful (BT,BT) broadcast ----
__global__ __launch_bounds__(256) void vf_kernel(
    const float* __restrict__ vpred, const float* __restrict__ ovp,
    const float* __restrict__ ret, float* __restrict__ scal)
{
    const int i = blockIdx.x;
    const float vp = vpred[i];
    float s = 0.f;
    for (int j = threadIdx.x; j < BT; j += 256) {
        float r = ret[j], o = ovp[j];
        float d = fminf(fmaxf(vp - o, -0.2f), 0.2f);
        float v1 = vp - r;     v1 *= v1;
        float v2 = o + d - r;  v2 *= v2;
        s += fmaxf(v1, v2);
    }
    for (int off = 32; off; off >>= 1) s += __shfl_down(s, off, 64);
    __shared__ float wsum[4];
    if ((threadIdx.x & 63) == 0) wsum[threadIdx.x >> 6] = s;
    __syncthreads();
    if (threadIdx.x == 0) atomicAdd(&scal[5], wsum[0] + wsum[1] + wsum[2] + wsum[3]);
}

// ---- finalize (dtype-flag-aware output) ----
__global__ void fin_kernel(const float* __restrict__ scal, const int* __restrict__ flag,
                           void* __restrict__ out) {
    float pg  = scal[2] / (float)BT;
    float ent = scal[3];
    float vf  = 0.5f * scal[5] / ((float)BT * (float)BT);
    float loss = pg - ent + vf;
    if (*flag) {
        float* o = (float*)out;
        o[0] = loss; o[1] = pg; o[2] = ent; o[3] = vf;
    } else {
        u16* o = (u16*)out;
        o[0] = f2b(loss); o[1] = f2b(pg); o[2] = f2b(ent); o[3] = f2b(vf);
    }
}

extern "C" void kernel_launch(void* const* d_in, const int* in_sizes, int n_in,
                              void* d_out, int out_size, void* d_ws, size_t ws_size,
                              hipStream_t stream)
{
    const int* mask = (const int*)d_in[1];
    const int* a_tk = (const int*)d_in[3];

    static const int sz[NSEG]  = {3407872, 4096, 4096, 4096, 4096, 512, 16, 2048, 32,
                                  8192, 64, 8192, 128, 262144, 262144, 1024,
                                  9216, 36, 1048576, 4096, 256, 1};
    static const int din[NSEG] = {0, 2, 4, 5, 6, 7, 8, 9, 10, 11, 12, 13, 14,
                                  15, 16, 17, 18, 19, 20, 21, 22, 23};
    Segs S;
    int off = 0;
    for (int s = 0; s < NSEG; s++) {
        S.src[s] = d_in[s == 0 ? 0 : din[s]];
        S.off[s] = off;
        S.size[s] = sz[s];
        off += (sz[s] + 3) & ~3;
    }
    S.off[NSEG] = off;

    float* arena = (float*)d_ws;
    const float* xa    = arena + S.off[0];
    const float* lgold = arena + S.off[1];
    const float* gae   = arena + S.off[2];
    const float* ovp   = arena + S.off[3];
    const float* ret   = arena + S.off[4];
    const float* W1 = arena + S.off[5],  *b1 = arena + S.off[6];
    const float* W2 = arena + S.off[7],  *b2 = arena + S.off[8];
    const float* W3 = arena + S.off[9],  *b3 = arena + S.off[10];
    const float* W4 = arena + S.off[11], *b4 = arena + S.off[12];
    const float* Wk = arena + S.off[13];
    const float* lb = arena + S.off[15];
    const float* pirW = arena + S.off[16], *pirB = arena + S.off[17];
    const float* pimB = arena + S.off[19];
    const float* vW   = arena + S.off[20], *vB   = arena + S.off[21];

    float* feat = arena + off;              // 1,048,576
    float* zx   = feat + 1048576;           // 4,194,304
    float* hseq = zx + 4194304;             // 1,048,576
    u16*   wrp  = (u16*)(hseq + 1048576);   // 262,144 u16 = 131,072 floats
    u16*   pimp = wrp + 262144;             // 1,048,576 u16 = 524,288 floats
    float* partS = hseq + 1048576 + 131072 + 524288;   // 65,536
    float* partU = partS + 65536;           // 65,536
    float* za    = partU + 65536;           // 4,096
    float* entpir = za + 4096;
    float* entpim = entpir + 4096;
    float* ppira  = entpim + 4096;
    float* ppima  = ppira + 4096;
    float* vpred  = ppima + 4096;
    float* scal   = vpred + 4096;           // 32 floats
    int*   flag   = (int*)(scal + 32);

    sniff_kernel<<<1, 256, 0, stream>>>((const u16*)d_in[15], flag, scal);
    convert_kernel<<<(S.off[NSEG] + 255) / 256, 256, 0, stream>>>(S, flag, arena);
    pack_wr_kernel<<<1024, 256, 0, stream>>>(d_in[16], flag, wrp);
    pack_pim_kernel<<<4096, 256, 0, stream>>>(d_in[20], flag, pimp);
    conv_kernel<<<BT, 128, 0, stream>>>(xa, W1, b1, W2, b2, W3, b3, W4, b4, feat);
    zx_kernel<<<dim3(4, 256), 256, 0, stream>>>(feat, Wk, lb, zx);
    lstm_kernel<<<NB, 1024, 0, stream>>>(zx, wrp, hseq);
    pir_kernel<<<BT, 64, 0, stream>>>(hseq, pirW, pirB, vW, vB, a_tk, entpir, ppira, vpred);
    pim_kernel<<<dim3(16, 256), 256, 0, stream>>>(hseq, pimp, pimB, mask, a_tk, partS, partU, za);
    pimfin_kernel<<<16, 256, 0, stream>>>(partS, partU, za, entpim, ppima);
    gae_kernel<<<1, 256, 0, stream>>>(gae, scal);
    pg_kernel<<<16, 256, 0, stream>>>(ppira, ppima, entpir, entpim, lgold, gae, scal);
    vf_kernel<<<BT, 256, 0, stream>>>(vpred, ovp, ret, scal);
    fin_kernel<<<1, 1, 0, stream>>>(scal, flag, (u16*)d_out);
}

// Round 4
// 652.855 us; speedup vs baseline: 2.4696x; 1.6203x over previous
//
#include <hip/hip_runtime.h>

typedef unsigned short u16;
typedef unsigned int   u32;

#define BT   4096
#define TSEQ 64
#define NB   64

typedef __attribute__((ext_vector_type(8))) short  short8;
typedef __attribute__((ext_vector_type(4))) float  f32x4;
typedef __attribute__((ext_vector_type(2))) _Float16 h2;

__device__ __forceinline__ float bf(u16 v) {
    u32 u = ((u32)v) << 16;
    return __builtin_bit_cast(float, u);
}
__device__ __forceinline__ u16 f2b(float f) {
    u32 u = __builtin_bit_cast(u32, f);
    return (u16)((u + 0x7fffu + ((u >> 16) & 1u)) >> 16);  // RNE
}
__device__ __forceinline__ float lrelu(float x) { return x > 0.f ? x : 0.2f * x; }
__device__ __forceinline__ h2 i2h(int v) { return __builtin_bit_cast(h2, v); }
__device__ __forceinline__ float dot2(int hbits, int wbits, float acc) {
#if __has_builtin(__builtin_amdgcn_fdot2)
    return __builtin_amdgcn_fdot2(i2h(hbits), i2h(wbits), acc, false);
#else
    h2 a = i2h(hbits), b = i2h(wbits);
    return acc + (float)a.x * (float)b.x + (float)a.y * (float)b.y;
#endif
}

#define NSEG 22
struct Segs { const void* src[NSEG]; int off[NSEG + 1]; int size[NSEG]; };

// ---- dtype sniff on lstm_k; also zeros scal ----
__global__ void sniff_kernel(const u16* __restrict__ probe, int* __restrict__ flag,
                             float* __restrict__ scal) {
    __shared__ int cnt[4];
    const int tid = threadIdx.x;
    int c = 0;
    for (int i = tid; i < 2048; i += 256) {
        u16 v = probe[2 * i];
        int e = (v >> 7) & 0xFF;
        if (v == 0 || (e >= 100 && e <= 130)) c++;
    }
    for (int off = 32; off; off >>= 1) c += __shfl_down(c, off, 64);
    if ((tid & 63) == 0) cnt[tid >> 6] = c;
    __syncthreads();
    if (tid == 0) {
        int t = cnt[0] + cnt[1] + cnt[2] + cnt[3];
        *flag = (t < 1024) ? 1 : 0;   // 1 = inputs are fp32
    }
    if (tid < 32) scal[tid] = 0.f;
}

// ---- canonicalize all float tensors into an fp32 arena ----
__global__ __launch_bounds__(256) void convert_kernel(Segs S, const int* __restrict__ flag,
                                                      float* __restrict__ arena) {
    const int gid = blockIdx.x * 256 + threadIdx.x;
    if (gid >= S.off[NSEG]) return;
    const int f32 = *flag;
    int s = 0;
    while (gid >= S.off[s + 1]) s++;
    const int i = gid - S.off[s];
    float v = 0.f;
    if (i < S.size[s])
        v = f32 ? ((const float*)S.src[s])[i] : bf(((const u16*)S.src[s])[i]);
    arena[gid] = v;
}

// ---- pack W (K=256 rows, N cols, row-major) -> bf16 MFMA B-fragment order ----
// dst u16 idx: (((k>>5)<<logN | col)*4 + ((k>>3)&3))*8 + (k&7)
__global__ void pack_bfrag(const void* __restrict__ W, const int* __restrict__ flag,
                           u16* __restrict__ dst, int logN) {
    int gid = blockIdx.x * 256 + threadIdx.x;
    int N = 1 << logN;
    int k = gid >> logN, col = gid & (N - 1);
    u16 v = (*flag) ? f2b(((const float*)W)[gid]) : ((const u16*)W)[gid];
    dst[((((size_t)(k >> 5) << logN) + col) * 4 + ((k >> 3) & 3)) * 8 + (k & 7)] = v;
}

// ---- pack Wr (256,1024) -> f16, PF[(k>>3)*1024+col]*8 + (k&7) ----
__global__ void pack_wr16(const void* __restrict__ W, const int* __restrict__ flag,
                          u16* __restrict__ dst) {
    int gid = blockIdx.x * 256 + threadIdx.x;   // 262144
    int k = gid >> 10, col = gid & 1023;
    float f = (*flag) ? ((const float*)W)[gid] : bf(((const u16*)W)[gid]);
    _Float16 h = (_Float16)f;
    dst[((size_t)(k >> 3) * 1024 + col) * 8 + (k & 7)] = __builtin_bit_cast(unsigned short, h);
}

// ---- fused conv stack: one block per image; writes bf16 feat ----
__global__ __launch_bounds__(128) void conv_kernel(
    const float* __restrict__ x,
    const float* __restrict__ W1, const float* __restrict__ b1,
    const float* __restrict__ W2, const float* __restrict__ b2,
    const float* __restrict__ W3, const float* __restrict__ b3,
    const float* __restrict__ W4, const float* __restrict__ b4,
    u16* __restrict__ featbf)
{
    __shared__ float xs[832];
    __shared__ float c1[384];
    __shared__ float c2[480];
    __shared__ float c3[128];
    const int bt = blockIdx.x, tid = threadIdx.x;

    for (int i = tid; i < 832; i += 128) xs[i] = x[bt * 832 + i];
    __syncthreads();

    for (int idx = tid; idx < 384; idx += 128) {
        int oc = idx & 15, ow = (idx >> 4) & 3, oh = idx >> 6;
        float acc = b1[oc];
        for (int kh = 0; kh < 2; kh++)
            for (int kw = 0; kw < 2; kw++) {
                const float* xp = &xs[(2 * oh + kh) * 64 + (2 * ow + kw) * 8];
                const float* wp = &W1[((kh * 2 + kw) * 8) * 16 + oc];
                for (int ic = 0; ic < 8; ic++) acc += xp[ic] * wp[ic * 16];
            }
        c1[idx] = lrelu(acc);
    }
    __syncthreads();

    for (int idx = tid; idx < 480; idx += 128) {
        int oc = idx & 31, ow = (idx >> 5) % 3, oh = idx / 96;
        float acc = b2[oc];
        for (int kh = 0; kh < 2; kh++)
            for (int kw = 0; kw < 2; kw++) {
                const float* ip = &c1[((oh + kh) * 4 + (ow + kw)) * 16];
                const float* wp = &W2[((kh * 2 + kw) * 16) * 32 + oc];
                for (int ic = 0; ic < 16; ic++) acc += ip[ic] * wp[ic * 32];
            }
        c2[idx] = lrelu(acc);
    }
    __syncthreads();

    for (int idx = tid; idx < 128; idx += 128) {
        int oc = idx & 63, oh = idx >> 6;
        float acc = b3[oc];
        for (int kh = 0; kh < 2; kh++)
            for (int kw = 0; kw < 2; kw++) {
                const float* ip = &c2[((2 * oh + kh) * 3 + kw) * 32];
                const float* wp = &W3[((kh * 2 + kw) * 32) * 64 + oc];
                for (int ic = 0; ic < 32; ic++) acc += ip[ic] * wp[ic * 64];
            }
        c3[idx] = lrelu(acc);
    }
    __syncthreads();

    for (int idx = tid; idx < 256; idx += 128) {
        int oh = idx & 1, oc = idx >> 1;
        float acc = b4[oc];
        const float* ip = &c3[oh * 64];
        for (int ic = 0; ic < 64; ic++) acc += ip[ic] * W4[ic * 128 + oc];
        featbf[bt * 256 + idx] = f2b(lrelu(acc));
    }
}

// ---- MFMA GEMM: zx = featbf(4096x256) @ Wk + b : out f32 (4096x1024) ----
__global__ __launch_bounds__(256) void gemm_zx(
    const u16* __restrict__ Abf, const u16* __restrict__ PB,
    const float* __restrict__ bias, float* __restrict__ out)
{
    __shared__ __align__(16) u16 As[16 * 264];
    const int mb = blockIdx.y, nb = blockIdx.x, tid = threadIdx.x;
    const int m0 = mb * 16;
    {
        int row = tid >> 4, part = tid & 15;
        const f32x4* src = (const f32x4*)&Abf[(size_t)(m0 + row) * 256 + part * 16];
        f32x4 v0 = src[0], v1 = src[1];
        *(f32x4*)&As[row * 264 + part * 16] = v0;
        *(f32x4*)&As[row * 264 + part * 16 + 8] = v1;
    }
    __syncthreads();
    const int wv = tid >> 6, lane = tid & 63;
    const int colw = lane & 15, q = lane >> 4;
    const int n = nb * 64 + wv * 16 + colw;
    f32x4 acc = {0.f, 0.f, 0.f, 0.f};
#pragma unroll
    for (int kt = 0; kt < 8; kt++) {
        short8 a = *(const short8*)&As[colw * 264 + kt * 32 + q * 8];
        short8 b = *(const short8*)&PB[((((size_t)kt << 10) + n) * 4 + q) * 8];
        acc = __builtin_amdgcn_mfma_f32_16x16x32_bf16(a, b, acc, 0, 0, 0);
    }
    const float bj = bias[n];
#pragma unroll
    for (int r = 0; r < 4; r++) {
        int row = q * 4 + r;
        out[(size_t)(m0 + row) * 1024 + n] = acc[r] + bj;
    }
}

// ---- MFMA GEMM + fused masked-softmax partials for pim ----
__global__ __launch_bounds__(256) void gemm_pim(
    const u16* __restrict__ Abf, const u16* __restrict__ PB,
    const float* __restrict__ bias,
    const int* __restrict__ mask, const int* __restrict__ a_taken,
    float* __restrict__ partS, float* __restrict__ partU, float* __restrict__ za)
{
    __shared__ __align__(16) u16 As[16 * 264];
    __shared__ float redS[4][16], redU[4][16];
    const int mb = blockIdx.y, nb = blockIdx.x, tid = threadIdx.x;
    const int m0 = mb * 16;
    {
        int row = tid >> 4, part = tid & 15;
        const f32x4* src = (const f32x4*)&Abf[(size_t)(m0 + row) * 256 + part * 16];
        f32x4 v0 = src[0], v1 = src[1];
        *(f32x4*)&As[row * 264 + part * 16] = v0;
        *(f32x4*)&As[row * 264 + part * 16 + 8] = v1;
    }
    __syncthreads();
    const int wv = tid >> 6, lane = tid & 63;
    const int colw = lane & 15, q = lane >> 4;
    const int n = nb * 64 + wv * 16 + colw;
    f32x4 acc = {0.f, 0.f, 0.f, 0.f};
#pragma unroll
    for (int kt = 0; kt < 8; kt++) {
        short8 a = *(const short8*)&As[colw * 264 + kt * 32 + q * 8];
        short8 b = *(const short8*)&PB[((((size_t)kt << 12) + n) * 4 + q) * 8];
        acc = __builtin_amdgcn_mfma_f32_16x16x32_bf16(a, b, acc, 0, 0, 0);
    }
    const float bj = bias[n];
    float sv[4], uv[4];
#pragma unroll
    for (int r = 0; r < 4; r++) {
        int row = m0 + q * 4 + r;
        float z = acc[r] + bj;
        int m = mask[(size_t)row * 4096 + n];
        float e = __expf(z);
        sv[r] = m ? e : 0.f;
        uv[r] = m ? e * z : 0.f;
        if (n == a_taken[row]) za[row] = z;
    }
#pragma unroll
    for (int r = 0; r < 4; r++) {
        for (int off = 1; off < 16; off <<= 1) {
            sv[r] += __shfl_xor(sv[r], off, 16);
            uv[r] += __shfl_xor(uv[r], off, 16);
        }
        if (colw == 0) { redS[wv][q * 4 + r] = sv[r]; redU[wv][q * 4 + r] = uv[r]; }
    }
    __syncthreads();
    if (tid < 16) {
        float S = redS[0][tid] + redS[1][tid] + redS[2][tid] + redS[3][tid];
        float U = redU[0][tid] + redU[1][tid] + redU[2][tid] + redU[3][tid];
        partS[(size_t)(m0 + tid) * 64 + nb] = S;
        partU[(size_t)(m0 + tid) * 64 + nb] = U;
    }
}

// ---- fold pim partials -> entropy + p[a] ----
__global__ __launch_bounds__(256) void pimfin_kernel(
    const float* __restrict__ partS, const float* __restrict__ partU,
    const float* __restrict__ za,
    float* __restrict__ entpim, float* __restrict__ ppima)
{
    const int r = blockIdx.x * 256 + threadIdx.x;
    float S = 0.f, U = 0.f;
#pragma unroll
    for (int t = 0; t < 64; t++) { S += partS[(size_t)r * 64 + t]; U += partU[(size_t)r * 64 + t]; }
    entpim[r] = logf(S) - U / S;
    ppima[r]  = __expf(za[r]) / S;
}

// ---- LSTM v3: f16 dot2, h broadcast via readlane, partial weight residency ----
#define NPRE 12
__global__ __launch_bounds__(1024) void lstm_kernel(
    const float* __restrict__ zx, const u16* __restrict__ PF,
    float* __restrict__ hseq, u16* __restrict__ hseqbf)
{
    __shared__ float zp[1024];
    __shared__ __align__(16) u16 h16[256];
    const int b = blockIdx.x, tid = threadIdx.x, lane = tid & 63;
    float c = 0.f;
    int hp0 = 0, hp1 = 0, hp2 = 0, hp3 = 0;
    const int4* Pw = (const int4*)PF;

    int4 wr[NPRE];
#pragma unroll
    for (int j = 0; j < NPRE; j++) wr[j] = Pw[j * 1024 + tid];

    for (int t = 0; t < TSEQ; t++) {
        float acc = zx[(size_t)(b * TSEQ + t) * 1024 + tid];
#pragma unroll
        for (int j = 0; j < 32; j++) {
            int4 w = (j < NPRE) ? wr[j] : Pw[j * 1024 + tid];
            int s0 = __builtin_amdgcn_readlane(hp0, j);
            int s1 = __builtin_amdgcn_readlane(hp1, j);
            int s2 = __builtin_amdgcn_readlane(hp2, j);
            int s3 = __builtin_amdgcn_readlane(hp3, j);
            acc = dot2(s0, w.x, acc);
            acc = dot2(s1, w.y, acc);
            acc = dot2(s2, w.z, acc);
            acc = dot2(s3, w.w, acc);
        }
        zp[tid] = acc;
        __syncthreads();
        if (tid < 256) {
            float ai = zp[tid], af = zp[256 + tid], ag = zp[512 + tid], ao = zp[768 + tid];
            float ig = 1.f / (1.f + __expf(-ai));
            float fg = 1.f / (1.f + __expf(-af));
            float og = 1.f / (1.f + __expf(-ao));
            float gg = tanhf(ag);
            c = fg * c + ig * gg;
            float h = og * tanhf(c);
            h16[tid] = __builtin_bit_cast(unsigned short, (_Float16)h);
            hseq[(size_t)(b * TSEQ + t) * 256 + tid] = h;
            hseqbf[(size_t)(b * TSEQ + t) * 256 + tid] = f2b(h);
        }
        __syncthreads();
        if (lane < 32) {
            int4 hv = *(const int4*)&h16[lane * 8];
            hp0 = hv.x; hp1 = hv.y; hp2 = hv.z; hp3 = hv.w;
        }
    }
}

// ---- pir head + vpred: one wave per row ----
__global__ __launch_bounds__(64) void pir_kernel(
    const float* __restrict__ hseq,
    const float* __restrict__ pir_W, const float* __restrict__ pir_b,
    const float* __restrict__ v_W, const float* __restrict__ v_b,
    const int* __restrict__ a_taken,
    float* __restrict__ entpir, float* __restrict__ ppira, float* __restrict__ vpred)
{
    __shared__ float hr[256];
    __shared__ float pz[36];
    const int r = blockIdx.x, tid = threadIdx.x;
    for (int i = tid; i < 256; i += 64) hr[i] = hseq[(size_t)r * 256 + i];
    __syncthreads();

    if (tid < 36) {
        float acc = pir_b[tid];
        for (int k = 0; k < 256; k++) acc += hr[k] * pir_W[k * 36 + tid];
        pz[tid] = acc;
    }
    float va = 0.f;
    for (int k = tid; k < 256; k += 64) va += hr[k] * v_W[k];
    for (int off = 32; off; off >>= 1) va += __shfl_down(va, off, 64);
    if (tid == 0) vpred[r] = va + v_b[0];
    __syncthreads();

    if (tid == 0) {
        float Z = 0.f, U = 0.f;
        for (int jj = 0; jj < 36; jj++) { float e = __expf(pz[jj]); Z += e; U += e * pz[jj]; }
        entpir[r] = logf(Z) - U / Z;
        ppira[r]  = __expf(pz[a_taken[r]]) / Z;
    }
}

// ---- GAE mean/std ----
__global__ __launch_bounds__(256) void gae_kernel(const float* __restrict__ g, float* scal) {
    const int tid = threadIdx.x;
    float s = 0.f, s2 = 0.f;
    for (int i = tid; i < BT; i += 256) { float v = g[i]; s += v; s2 += v * v; }
    for (int off = 32; off; off >>= 1) { s += __shfl_down(s, off, 64); s2 += __shfl_down(s2, off, 64); }
    __shared__ float wsx[8];
    const int w = tid >> 6;
    if ((tid & 63) == 0) { wsx[w] = s; wsx[4 + w] = s2; }
    __syncthreads();
    if (tid == 0) {
        float S = 0.f, S2 = 0.f;
        for (int i = 0; i < 4; i++) { S += wsx[i]; S2 += wsx[4 + i]; }
        float mean = S / (float)BT;
        float var = S2 / (float)BT - mean * mean;
        scal[0] = mean;
        scal[1] = sqrtf(fmaxf(var, 0.f));
    }
}

// ---- pg loss + entropy sums ----
__global__ __launch_bounds__(256) void pg_kernel(
    const float* __restrict__ ppira, const float* __restrict__ ppima,
    const float* __restrict__ entpir, const float* __restrict__ entpim,
    const float* __restrict__ lgold, const float* __restrict__ gae,
    float* __restrict__ scal)
{
    const int t = blockIdx.x * 256 + threadIdx.x;
    const float mean = scal[0], sd = scal[1];
    float p  = (t & 1) ? ppima[t] : ppira[t];
    float ln = logf(p);
    float rt = __expf(ln - lgold[t]);
    float g  = (gae[t] - mean) / (sd + 1e-8f);
    float rtc = fminf(fmaxf(rt, 0.8f), 1.2f);
    float pg = fmaxf(-g * rt, -g * rtc);
    float e1 = entpir[t], e2 = entpim[t];
    for (int off = 32; off; off >>= 1) {
        pg += __shfl_down(pg, off, 64);
        e1 += __shfl_down(e1, off, 64);
        e2 += __shfl_down(e2, off, 64);
    }
    if ((threadIdx.x & 63) == 0) {
        atomicAdd(&scal[2], pg);
        atomicAdd(&scal[3], e1 + e2);
    }
}

// ---- vf loss: faithful (BT,BT) broadcast ----
__global__ __launch_bounds__(256) void vf_kernel(
    const float* __restrict__ vpred, const float* __restrict__ ovp,
    const float* __restrict__ ret, float* __restrict__ scal)
{
    const int i = blockIdx.x;
    const float vp = vpred[i];
    float s = 0.f;
    for (int j = threadIdx.x; j < BT; j += 256) {
        float r = ret[j], o = ovp[j];
        float d = fminf(fmaxf(vp - o, -0.2f), 0.2f);
        float v1 = vp - r;     v1 *= v1;
        float v2 = o + d - r;  v2 *= v2;
        s += fmaxf(v1, v2);
    }
    for (int off = 32; off; off >>= 1) s += __shfl_down(s, off, 64);
    __shared__ float wsum[4];
    if ((threadIdx.x & 63) == 0) wsum[threadIdx.x >> 6] = s;
    __syncthreads();
    if (threadIdx.x == 0) atomicAdd(&scal[5], wsum[0] + wsum[1] + wsum[2] + wsum[3]);
}

// ---- finalize ----
__global__ void fin_kernel(const float* __restrict__ scal, const int* __restrict__ flag,
                           void* __restrict__ out) {
    float pg  = scal[2] / (float)BT;
    float ent = scal[3];
    float vf  = 0.5f * scal[5] / ((float)BT * (float)BT);
    float loss = pg - ent + vf;
    if (*flag) {
        float* o = (float*)out;
        o[0] = loss; o[1] = pg; o[2] = ent; o[3] = vf;
    } else {
        u16* o = (u16*)out;
        o[0] = f2b(loss); o[1] = f2b(pg); o[2] = f2b(ent); o[3] = f2b(vf);
    }
}

extern "C" void kernel_launch(void* const* d_in, const int* in_sizes, int n_in,
                              void* d_out, int out_size, void* d_ws, size_t ws_size,
                              hipStream_t stream)
{
    const int* mask = (const int*)d_in[1];
    const int* a_tk = (const int*)d_in[3];

    static const int sz[NSEG]  = {3407872, 4096, 4096, 4096, 4096, 512, 16, 2048, 32,
                                  8192, 64, 8192, 128, 262144, 262144, 1024,
                                  9216, 36, 1048576, 4096, 256, 1};
    static const int din[NSEG] = {0, 2, 4, 5, 6, 7, 8, 9, 10, 11, 12, 13, 14,
                                  15, 16, 17, 18, 19, 20, 21, 22, 23};
    Segs S;
    int off = 0;
    for (int s = 0; s < NSEG; s++) {
        S.src[s] = d_in[din[s]];
        S.off[s] = off;
        S.size[s] = sz[s];
        off += (sz[s] + 3) & ~3;
    }
    S.off[NSEG] = off;   // 5,030,940 floats

    float* arena = (float*)d_ws;
    const float* xa    = arena + S.off[0];
    const float* lgold = arena + S.off[1];
    const float* gae   = arena + S.off[2];
    const float* ovp   = arena + S.off[3];
    const float* ret   = arena + S.off[4];
    const float* W1 = arena + S.off[5],  *b1 = arena + S.off[6];
    const float* W2 = arena + S.off[7],  *b2 = arena + S.off[8];
    const float* W3 = arena + S.off[9],  *b3 = arena + S.off[10];
    const float* W4 = arena + S.off[11], *b4 = arena + S.off[12];
    const float* lb = arena + S.off[15];
    const float* pirW = arena + S.off[16], *pirB = arena + S.off[17];
    const float* pimB = arena + S.off[19];
    const float* vW   = arena + S.off[20], *vB   = arena + S.off[21];

    // scratch after arena
    float* p = arena + off;
    u16*   featbf = (u16*)p;            p += 524288;    // 1M u16
    float* zx     = p;                  p += 4194304;
    float* hseq   = p;                  p += 1048576;
    u16*   hseqbf = (u16*)p;            p += 524288;    // 1M u16
    u16*   PF     = (u16*)p;            p += 131072;    // 256K u16 (f16 Wr)
    u16*   PBk    = (u16*)p;            p += 131072;    // 256K u16 (bf16 Wk frag)
    u16*   PBpim  = (u16*)p;            p += 524288;    // 1M u16 (bf16 pimW frag)
    float* scal   = p;                  p += 32;
    int*   flag   = (int*)p;

    // alias small post-conv buffers onto the x-arena region (x consumed by conv)
    float* q = (float*)(arena + S.off[0]);
    float* partS  = q;                  q += 262144;    // [4096][64]
    float* partU  = q;                  q += 262144;
    float* za     = q;                  q += 4096;
    float* entpir = q;                  q += 4096;
    float* entpim = q;                  q += 4096;
    float* ppira  = q;                  q += 4096;
    float* ppima  = q;                  q += 4096;
    float* vpred  = q;                  q += 4096;

    sniff_kernel<<<1, 256, 0, stream>>>((const u16*)d_in[15], flag, scal);
    convert_kernel<<<(S.off[NSEG] + 255) / 256, 256, 0, stream>>>(S, flag, arena);
    pack_wr16<<<1024, 256, 0, stream>>>(d_in[16], flag, PF);
    pack_bfrag<<<1024, 256, 0, stream>>>(d_in[15], flag, PBk, 10);
    pack_bfrag<<<4096, 256, 0, stream>>>(d_in[20], flag, PBpim, 12);
    conv_kernel<<<BT, 128, 0, stream>>>(xa, W1, b1, W2, b2, W3, b3, W4, b4, featbf);
    gemm_zx<<<dim3(16, 256), 256, 0, stream>>>(featbf, PBk, lb, zx);
    lstm_kernel<<<NB, 1024, 0, stream>>>(zx, PF, hseq, hseqbf);
    pir_kernel<<<BT, 64, 0, stream>>>(hseq, pirW, pirB, vW, vB, a_tk, entpir, ppira, vpred);
    gemm_pim<<<dim3(64, 256), 256, 0, stream>>>(hseqbf, PBpim, pimB, mask, a_tk, partS, partU, za);
    pimfin_kernel<<<16, 256, 0, stream>>>(partS, partU, za, entpim, ppima);
    gae_kernel<<<1, 256, 0, stream>>>(gae, scal);
    pg_kernel<<<16, 256, 0, stream>>>(ppira, ppima, entpir, entpim, lgold, gae, scal);
    vf_kernel<<<BT, 256, 0, stream>>>(vpred, ovp, ret, scal);
    fin_kernel<<<1, 1, 0, stream>>>(scal, flag, (u16*)d_out);
}

// Round 5
// 612.929 us; speedup vs baseline: 2.6304x; 1.0651x over previous
//
#include <hip/hip_runtime.h>

typedef unsigned short u16;
typedef unsigned int   u32;

#define BT   4096
#define TSEQ 64
#define NB   64

typedef __attribute__((ext_vector_type(8))) short  short8;
typedef __attribute__((ext_vector_type(4))) float  f32x4;
typedef __attribute__((ext_vector_type(2))) _Float16 h2;

__device__ __forceinline__ float bf(u16 v) {
    u32 u = ((u32)v) << 16;
    return __builtin_bit_cast(float, u);
}
__device__ __forceinline__ u16 f2b(float f) {
    u32 u = __builtin_bit_cast(u32, f);
    return (u16)((u + 0x7fffu + ((u >> 16) & 1u)) >> 16);  // RNE
}
__device__ __forceinline__ float lrelu(float x) { return x > 0.f ? x : 0.2f * x; }
__device__ __forceinline__ h2 i2h(int v) { return __builtin_bit_cast(h2, v); }
__device__ __forceinline__ float dot2(int hbits, int wbits, float acc) {
#if __has_builtin(__builtin_amdgcn_fdot2)
    return __builtin_amdgcn_fdot2(i2h(hbits), i2h(wbits), acc, false);
#else
    h2 a = i2h(hbits), b = i2h(wbits);
    return acc + (float)a.x * (float)b.x + (float)a.y * (float)b.y;
#endif
}

#define NSEG 22
struct Segs { const void* src[NSEG]; int off[NSEG + 1]; int size[NSEG]; };

// ---- dtype sniff on lstm_k; also zeros scal ----
__global__ void sniff_kernel(const u16* __restrict__ probe, int* __restrict__ flag,
                             float* __restrict__ scal) {
    __shared__ int cnt[4];
    const int tid = threadIdx.x;
    int c = 0;
    for (int i = tid; i < 2048; i += 256) {
        u16 v = probe[2 * i];
        int e = (v >> 7) & 0xFF;
        if (v == 0 || (e >= 100 && e <= 130)) c++;
    }
    for (int off = 32; off; off >>= 1) c += __shfl_down(c, off, 64);
    if ((tid & 63) == 0) cnt[tid >> 6] = c;
    __syncthreads();
    if (tid == 0) {
        int t = cnt[0] + cnt[1] + cnt[2] + cnt[3];
        *flag = (t < 1024) ? 1 : 0;   // 1 = inputs are fp32
    }
    if (tid < 32) scal[tid] = 0.f;
}

// ---- canonicalize all float tensors into an fp32 arena ----
__global__ __launch_bounds__(256) void convert_kernel(Segs S, const int* __restrict__ flag,
                                                      float* __restrict__ arena) {
    const int gid = blockIdx.x * 256 + threadIdx.x;
    if (gid >= S.off[NSEG]) return;
    const int f32 = *flag;
    int s = 0;
    while (gid >= S.off[s + 1]) s++;
    const int i = gid - S.off[s];
    float v = 0.f;
    if (i < S.size[s])
        v = f32 ? ((const float*)S.src[s])[i] : bf(((const u16*)S.src[s])[i]);
    arena[gid] = v;
}

// ---- fused packing: Wr->f16 chunks, Wk/pimW -> bf16 MFMA B-fragment order ----
__global__ __launch_bounds__(256) void pack_all(
    const void* __restrict__ Wr, const void* __restrict__ Wk,
    const void* __restrict__ Wpim, const int* __restrict__ flag,
    u16* __restrict__ PF, u16* __restrict__ PBk, u16* __restrict__ PBpim)
{
    const int blk = blockIdx.x, tid = threadIdx.x;
    const int f32 = *flag;
    if (blk < 1024) {
        int gid = blk * 256 + tid;
        int k = gid >> 10, col = gid & 1023;
        float f = f32 ? ((const float*)Wr)[gid] : bf(((const u16*)Wr)[gid]);
        _Float16 h = (_Float16)f;
        PF[((size_t)(k >> 3) * 1024 + col) * 8 + (k & 7)] =
            __builtin_bit_cast(unsigned short, h);
    } else if (blk < 2048) {
        int gid = (blk - 1024) * 256 + tid;
        int k = gid >> 10, col = gid & 1023;
        u16 v = f32 ? f2b(((const float*)Wk)[gid]) : ((const u16*)Wk)[gid];
        PBk[((((size_t)(k >> 5) << 10) + col) * 4 + ((k >> 3) & 3)) * 8 + (k & 7)] = v;
    } else {
        int gid = (blk - 2048) * 256 + tid;
        int k = gid >> 12, col = gid & 4095;
        u16 v = f32 ? f2b(((const float*)Wpim)[gid]) : ((const u16*)Wpim)[gid];
        PBpim[((((size_t)(k >> 5) << 12) + col) * 4 + ((k >> 3) & 3)) * 8 + (k & 7)] = v;
    }
}

// ---- fused conv stack: one block per image; writes bf16 feat ----
__global__ __launch_bounds__(128) void conv_kernel(
    const float* __restrict__ x,
    const float* __restrict__ W1, const float* __restrict__ b1,
    const float* __restrict__ W2, const float* __restrict__ b2,
    const float* __restrict__ W3, const float* __restrict__ b3,
    const float* __restrict__ W4, const float* __restrict__ b4,
    u16* __restrict__ featbf)
{
    __shared__ float xs[832];
    __shared__ float c1[384];
    __shared__ float c2[480];
    __shared__ float c3[128];
    const int bt = blockIdx.x, tid = threadIdx.x;

    for (int i = tid; i < 832; i += 128) xs[i] = x[bt * 832 + i];
    __syncthreads();

    for (int idx = tid; idx < 384; idx += 128) {
        int oc = idx & 15, ow = (idx >> 4) & 3, oh = idx >> 6;
        float acc = b1[oc];
        for (int kh = 0; kh < 2; kh++)
            for (int kw = 0; kw < 2; kw++) {
                const float* xp = &xs[(2 * oh + kh) * 64 + (2 * ow + kw) * 8];
                const float* wp = &W1[((kh * 2 + kw) * 8) * 16 + oc];
                for (int ic = 0; ic < 8; ic++) acc += xp[ic] * wp[ic * 16];
            }
        c1[idx] = lrelu(acc);
    }
    __syncthreads();

    for (int idx = tid; idx < 480; idx += 128) {
        int oc = idx & 31, ow = (idx >> 5) % 3, oh = idx / 96;
        float acc = b2[oc];
        for (int kh = 0; kh < 2; kh++)
            for (int kw = 0; kw < 2; kw++) {
                const float* ip = &c1[((oh + kh) * 4 + (ow + kw)) * 16];
                const float* wp = &W2[((kh * 2 + kw) * 16) * 32 + oc];
                for (int ic = 0; ic < 16; ic++) acc += ip[ic] * wp[ic * 32];
            }
        c2[idx] = lrelu(acc);
    }
    __syncthreads();

    for (int idx = tid; idx < 128; idx += 128) {
        int oc = idx & 63, oh = idx >> 6;
        float acc = b3[oc];
        for (int kh = 0; kh < 2; kh++)
            for (int kw = 0; kw < 2; kw++) {
                const float* ip = &c2[((2 * oh + kh) * 3 + kw) * 32];
                const float* wp = &W3[((kh * 2 + kw) * 32) * 64 + oc];
                for (int ic = 0; ic < 32; ic++) acc += ip[ic] * wp[ic * 64];
            }
        c3[idx] = lrelu(acc);
    }
    __syncthreads();

    for (int idx = tid; idx < 256; idx += 128) {
        int oh = idx & 1, oc = idx >> 1;
        float acc = b4[oc];
        const float* ip = &c3[oh * 64];
        for (int ic = 0; ic < 64; ic++) acc += ip[ic] * W4[ic * 128 + oc];
        featbf[bt * 256 + idx] = f2b(lrelu(acc));
    }
}

// ---- MFMA GEMM: zx = featbf(4096x256) @ Wk + b : out f32 (4096x1024) ----
__global__ __launch_bounds__(256) void gemm_zx(
    const u16* __restrict__ Abf, const u16* __restrict__ PB,
    const float* __restrict__ bias, float* __restrict__ out)
{
    __shared__ __align__(16) u16 As[16 * 264];
    const int mb = blockIdx.y, nb = blockIdx.x, tid = threadIdx.x;
    const int m0 = mb * 16;
    {
        int row = tid >> 4, part = tid & 15;
        const f32x4* src = (const f32x4*)&Abf[(size_t)(m0 + row) * 256 + part * 16];
        f32x4 v0 = src[0], v1 = src[1];
        *(f32x4*)&As[row * 264 + part * 16] = v0;
        *(f32x4*)&As[row * 264 + part * 16 + 8] = v1;
    }
    __syncthreads();
    const int wv = tid >> 6, lane = tid & 63;
    const int colw = lane & 15, q = lane >> 4;
    const int n = nb * 64 + wv * 16 + colw;
    f32x4 acc = {0.f, 0.f, 0.f, 0.f};
#pragma unroll
    for (int kt = 0; kt < 8; kt++) {
        short8 a = *(const short8*)&As[colw * 264 + kt * 32 + q * 8];
        short8 b = *(const short8*)&PB[((((size_t)kt << 10) + n) * 4 + q) * 8];
        acc = __builtin_amdgcn_mfma_f32_16x16x32_bf16(a, b, acc, 0, 0, 0);
    }
    const float bj = bias[n];
#pragma unroll
    for (int r = 0; r < 4; r++) {
        int row = q * 4 + r;
        out[(size_t)(m0 + row) * 1024 + n] = acc[r] + bj;
    }
}

// ---- MFMA GEMM + fused masked-softmax partials for pim ----
__global__ __launch_bounds__(256) void gemm_pim(
    const u16* __restrict__ Abf, const u16* __restrict__ PB,
    const float* __restrict__ bias,
    const int* __restrict__ mask, const int* __restrict__ a_taken,
    float* __restrict__ partS, float* __restrict__ partU, float* __restrict__ za)
{
    __shared__ __align__(16) u16 As[16 * 264];
    __shared__ float redS[4][16], redU[4][16];
    const int mb = blockIdx.y, nb = blockIdx.x, tid = threadIdx.x;
    const int m0 = mb * 16;
    {
        int row = tid >> 4, part = tid & 15;
        const f32x4* src = (const f32x4*)&Abf[(size_t)(m0 + row) * 256 + part * 16];
        f32x4 v0 = src[0], v1 = src[1];
        *(f32x4*)&As[row * 264 + part * 16] = v0;
        *(f32x4*)&As[row * 264 + part * 16 + 8] = v1;
    }
    __syncthreads();
    const int wv = tid >> 6, lane = tid & 63;
    const int colw = lane & 15, q = lane >> 4;
    const int n = nb * 64 + wv * 16 + colw;
    f32x4 acc = {0.f, 0.f, 0.f, 0.f};
#pragma unroll
    for (int kt = 0; kt < 8; kt++) {
        short8 a = *(const short8*)&As[colw * 264 + kt * 32 + q * 8];
        short8 b = *(const short8*)&PB[((((size_t)kt << 12) + n) * 4 + q) * 8];
        acc = __builtin_amdgcn_mfma_f32_16x16x32_bf16(a, b, acc, 0, 0, 0);
    }
    const float bj = bias[n];
    float sv[4], uv[4];
#pragma unroll
    for (int r = 0; r < 4; r++) {
        int row = m0 + q * 4 + r;
        float z = acc[r] + bj;
        int m = mask[(size_t)row * 4096 + n];
        float e = __expf(z);
        sv[r] = m ? e : 0.f;
        uv[r] = m ? e * z : 0.f;
        if (n == a_taken[row]) za[row] = z;
    }
#pragma unroll
    for (int r = 0; r < 4; r++) {
        for (int off = 1; off < 16; off <<= 1) {
            sv[r] += __shfl_xor(sv[r], off, 16);
            uv[r] += __shfl_xor(uv[r], off, 16);
        }
        if (colw == 0) { redS[wv][q * 4 + r] = sv[r]; redU[wv][q * 4 + r] = uv[r]; }
    }
    __syncthreads();
    if (tid < 16) {
        float S = redS[0][tid] + redS[1][tid] + redS[2][tid] + redS[3][tid];
        float U = redU[0][tid] + redU[1][tid] + redU[2][tid] + redU[3][tid];
        partS[(size_t)(m0 + tid) * 64 + nb] = S;
        partU[(size_t)(m0 + tid) * 64 + nb] = U;
    }
}

// ---- fold pim partials + GAE stats (merged) ----
__global__ __launch_bounds__(256) void pimfin_gae_kernel(
    const float* __restrict__ partS, const float* __restrict__ partU,
    const float* __restrict__ za,
    float* __restrict__ entpim, float* __restrict__ ppima,
    const float* __restrict__ g, float* __restrict__ scal)
{
    const int tid = threadIdx.x;
    if (blockIdx.x < 16) {
        const int r = blockIdx.x * 256 + tid;
        float S = 0.f, U = 0.f;
#pragma unroll
        for (int t = 0; t < 64; t++) { S += partS[(size_t)r * 64 + t]; U += partU[(size_t)r * 64 + t]; }
        entpim[r] = logf(S) - U / S;
        ppima[r]  = __expf(za[r]) / S;
    } else {
        float s = 0.f, s2 = 0.f;
        for (int i = tid; i < BT; i += 256) { float v = g[i]; s += v; s2 += v * v; }
        for (int off = 32; off; off >>= 1) { s += __shfl_down(s, off, 64); s2 += __shfl_down(s2, off, 64); }
        __shared__ float wsx[8];
        const int w = tid >> 6;
        if ((tid & 63) == 0) { wsx[w] = s; wsx[4 + w] = s2; }
        __syncthreads();
        if (tid == 0) {
            float S = 0.f, S2 = 0.f;
            for (int i = 0; i < 4; i++) { S += wsx[i]; S2 += wsx[4 + i]; }
            float mean = S / (float)BT;
            float var = S2 / (float)BT - mean * mean;
            scal[0] = mean;
            scal[1] = sqrtf(fmaxf(var, 0.f));
        }
    }
}

// ---- LSTM v4: weights mostly register-resident, h broadcast from LDS ----
#define NPRE 24
__global__ __launch_bounds__(1024) void lstm_kernel(
    const float* __restrict__ zx, const u16* __restrict__ PF,
    float* __restrict__ hseq, u16* __restrict__ hseqbf)
{
    __shared__ float zp[1024];
    __shared__ __align__(16) u16 h16[256];
    const int b = blockIdx.x, tid = threadIdx.x;
    float c = 0.f;
    const int4* Pw = (const int4*)PF;

    int4 wr[NPRE];
#pragma unroll
    for (int j = 0; j < NPRE; j++) wr[j] = Pw[j * 1024 + tid];
    if (tid < 256) h16[tid] = 0;
    __syncthreads();

    for (int t = 0; t < TSEQ; t++) {
        float acc0 = zx[(size_t)(b * TSEQ + t) * 1024 + tid];
        float acc1 = 0.f, acc2 = 0.f, acc3 = 0.f;
#pragma unroll
        for (int j = 0; j < NPRE; j++) {
            int4 hv = *(const int4*)&h16[j * 8];   // wave-uniform: LDS broadcast
            acc0 = dot2(hv.x, wr[j].x, acc0);
            acc1 = dot2(hv.y, wr[j].y, acc1);
            acc2 = dot2(hv.z, wr[j].z, acc2);
            acc3 = dot2(hv.w, wr[j].w, acc3);
        }
#pragma unroll
        for (int j = NPRE; j < 32; j++) {
            int4 w = Pw[j * 1024 + tid];
            int4 hv = *(const int4*)&h16[j * 8];
            acc0 = dot2(hv.x, w.x, acc0);
            acc1 = dot2(hv.y, w.y, acc1);
            acc2 = dot2(hv.z, w.z, acc2);
            acc3 = dot2(hv.w, w.w, acc3);
        }
        zp[tid] = (acc0 + acc1) + (acc2 + acc3);
        __syncthreads();           // gate pre-acts ready; h16 reads done
        if (tid < 256) {
            float ai = zp[tid], af = zp[256 + tid], ag = zp[512 + tid], ao = zp[768 + tid];
            float ig = 1.f / (1.f + __expf(-ai));
            float fg = 1.f / (1.f + __expf(-af));
            float og = 1.f / (1.f + __expf(-ao));
            float gg = tanhf(ag);
            c = fg * c + ig * gg;
            float h = og * tanhf(c);
            h16[tid] = __builtin_bit_cast(unsigned short, (_Float16)h);
            hseq[(size_t)(b * TSEQ + t) * 256 + tid] = h;
            hseqbf[(size_t)(b * TSEQ + t) * 256 + tid] = f2b(h);
        }
        __syncthreads();           // new h16 visible
    }
}

// ---- pir head + vpred: one wave per row ----
__global__ __launch_bounds__(64) void pir_kernel(
    const float* __restrict__ hseq,
    const float* __restrict__ pir_W, const float* __restrict__ pir_b,
    const float* __restrict__ v_W, const float* __restrict__ v_b,
    const int* __restrict__ a_taken,
    float* __restrict__ entpir, float* __restrict__ ppira, float* __restrict__ vpred)
{
    __shared__ float hr[256];
    __shared__ float pz[36];
    const int r = blockIdx.x, tid = threadIdx.x;
    for (int i = tid; i < 256; i += 64) hr[i] = hseq[(size_t)r * 256 + i];
    __syncthreads();

    if (tid < 36) {
        float acc = pir_b[tid];
        for (int k = 0; k < 256; k++) acc += hr[k] * pir_W[k * 36 + tid];
        pz[tid] = acc;
    }
    float va = 0.f;
    for (int k = tid; k < 256; k += 64) va += hr[k] * v_W[k];
    for (int off = 32; off; off >>= 1) va += __shfl_down(va, off, 64);
    if (tid == 0) vpred[r] = va + v_b[0];
    __syncthreads();

    if (tid == 0) {
        float Z = 0.f, U = 0.f;
        for (int jj = 0; jj < 36; jj++) { float e = __expf(pz[jj]); Z += e; U += e * pz[jj]; }
        entpir[r] = logf(Z) - U / Z;
        ppira[r]  = __expf(pz[a_taken[r]]) / Z;
    }
}

// ---- pg loss + entropy sums ----
__global__ __launch_bounds__(256) void pg_kernel(
    const float* __restrict__ ppira, const float* __restrict__ ppima,
    const float* __restrict__ entpir, const float* __restrict__ entpim,
    const float* __restrict__ lgold, const float* __restrict__ gae,
    float* __restrict__ scal)
{
    const int t = blockIdx.x * 256 + threadIdx.x;
    const float mean = scal[0], sd = scal[1];
    float p  = (t & 1) ? ppima[t] : ppira[t];
    float ln = logf(p);
    float rt = __expf(ln - lgold[t]);
    float g  = (gae[t] - mean) / (sd + 1e-8f);
    float rtc = fminf(fmaxf(rt, 0.8f), 1.2f);
    float pg = fmaxf(-g * rt, -g * rtc);
    float e1 = entpir[t], e2 = entpim[t];
    for (int off = 32; off; off >>= 1) {
        pg += __shfl_down(pg, off, 64);
        e1 += __shfl_down(e1, off, 64);
        e2 += __shfl_down(e2, off, 64);
    }
    if ((threadIdx.x & 63) == 0) {
        atomicAdd(&scal[2], pg);
        atomicAdd(&scal[3], e1 + e2);
    }
}

// ---- vf loss: faithful (BT,BT) broadcast ----
__global__ __launch_bounds__(256) void vf_kernel(
    const float* __restrict__ vpred, const float* __restrict__ ovp,
    const float* __restrict__ ret, float* __restrict__ scal)
{
    const int i = blockIdx.x;
    const float vp = vpred[i];
    float s = 0.f;
    for (int j = threadIdx.x; j < BT; j += 256) {
        float r = ret[j], o = ovp[j];
        float d = fminf(fmaxf(vp - o, -0.2f), 0.2f);
        float v1 = vp - r;     v1 *= v1;
        float v2 = o + d - r;  v2 *= v2;
        s += fmaxf(v1, v2);
    }
    for (int off = 32; off; off >>= 1) s += __shfl_down(s, off, 64);
    __shared__ float wsum[4];
    if ((threadIdx.x & 63) == 0) wsum[threadIdx.x >> 6] = s;
    __syncthreads();
    if (threadIdx.x == 0) atomicAdd(&scal[5], wsum[0] + wsum[1] + wsum[2] + wsum[3]);
}

// ---- finalize ----
__global__ void fin_kernel(const float* __restrict__ scal, const int* __restrict__ flag,
                           void* __restrict__ out) {
    float pg  = scal[2] / (float)BT;
    float ent = scal[3];
    float vf  = 0.5f * scal[5] / ((float)BT * (float)BT);
    float loss = pg - ent + vf;
    if (*flag) {
        float* o = (float*)out;
        o[0] = loss; o[1] = pg; o[2] = ent; o[3] = vf;
    } else {
        u16* o = (u16*)out;
        o[0] = f2b(loss); o[1] = f2b(pg); o[2] = f2b(ent); o[3] = f2b(vf);
    }
}

extern "C" void kernel_launch(void* const* d_in, const int* in_sizes, int n_in,
                              void* d_out, int out_size, void* d_ws, size_t ws_size,
                              hipStream_t stream)
{
    const int* mask = (const int*)d_in[1];
    const int* a_tk = (const int*)d_in[3];

    static const int sz[NSEG]  = {3407872, 4096, 4096, 4096, 4096, 512, 16, 2048, 32,
                                  8192, 64, 8192, 128, 262144, 262144, 1024,
                                  9216, 36, 1048576, 4096, 256, 1};
    static const int din[NSEG] = {0, 2, 4, 5, 6, 7, 8, 9, 10, 11, 12, 13, 14,
                                  15, 16, 17, 18, 19, 20, 21, 22, 23};
    Segs S;
    int off = 0;
    for (int s = 0; s < NSEG; s++) {
        S.src[s] = d_in[din[s]];
        S.off[s] = off;
        S.size[s] = sz[s];
        off += (sz[s] + 3) & ~3;
    }
    S.off[NSEG] = off;

    float* arena = (float*)d_ws;
    const float* xa    = arena + S.off[0];
    const float* lgold = arena + S.off[1];
    const float* gae   = arena + S.off[2];
    const float* ovp   = arena + S.off[3];
    const float* ret   = arena + S.off[4];
    const float* W1 = arena + S.off[5],  *b1 = arena + S.off[6];
    const float* W2 = arena + S.off[7],  *b2 = arena + S.off[8];
    const float* W3 = arena + S.off[9],  *b3 = arena + S.off[10];
    const float* W4 = arena + S.off[11], *b4 = arena + S.off[12];
    const float* lb = arena + S.off[15];
    const float* pirW = arena + S.off[16], *pirB = arena + S.off[17];
    const float* pimB = arena + S.off[19];
    const float* vW   = arena + S.off[20], *vB   = arena + S.off[21];

    // scratch after arena
    float* p = arena + off;
    u16*   featbf = (u16*)p;            p += 524288;
    float* zx     = p;                  p += 4194304;
    float* hseq   = p;                  p += 1048576;
    u16*   hseqbf = (u16*)p;            p += 524288;
    u16*   PF     = (u16*)p;            p += 131072;
    u16*   PBk    = (u16*)p;            p += 131072;
    u16*   PBpim  = (u16*)p;            p += 524288;
    float* scal   = p;                  p += 32;
    int*   flag   = (int*)p;

    // alias small post-conv buffers onto the x-arena region (x consumed by conv)
    float* q = (float*)(arena + S.off[0]);
    float* partS  = q;                  q += 262144;
    float* partU  = q;                  q += 262144;
    float* za     = q;                  q += 4096;
    float* entpir = q;                  q += 4096;
    float* entpim = q;                  q += 4096;
    float* ppira  = q;                  q += 4096;
    float* ppima  = q;                  q += 4096;
    float* vpred  = q;                  q += 4096;

    sniff_kernel<<<1, 256, 0, stream>>>((const u16*)d_in[15], flag, scal);
    convert_kernel<<<(S.off[NSEG] + 255) / 256, 256, 0, stream>>>(S, flag, arena);
    pack_all<<<6144, 256, 0, stream>>>(d_in[16], d_in[15], d_in[20], flag, PF, PBk, PBpim);
    conv_kernel<<<BT, 128, 0, stream>>>(xa, W1, b1, W2, b2, W3, b3, W4, b4, featbf);
    gemm_zx<<<dim3(16, 256), 256, 0, stream>>>(featbf, PBk, lb, zx);
    lstm_kernel<<<NB, 1024, 0, stream>>>(zx, PF, hseq, hseqbf);
    pir_kernel<<<BT, 64, 0, stream>>>(hseq, pirW, pirB, vW, vB, a_tk, entpir, ppira, vpred);
    gemm_pim<<<dim3(64, 256), 256, 0, stream>>>(hseqbf, PBpim, pimB, mask, a_tk, partS, partU, za);
    pimfin_gae_kernel<<<17, 256, 0, stream>>>(partS, partU, za, entpim, ppima, gae, scal);
    pg_kernel<<<16, 256, 0, stream>>>(ppira, ppima, entpir, entpim, lgold, gae, scal);
    vf_kernel<<<BT, 256, 0, stream>>>(vpred, ovp, ret, scal);
    fin_kernel<<<1, 1, 0, stream>>>(scal, flag, (u16*)d_out);
}

// Round 7
// 580.314 us; speedup vs baseline: 2.7783x; 1.0562x over previous
//
#include <hip/hip_runtime.h>

typedef unsigned short u16;
typedef unsigned int   u32;

#define BT   4096
#define TSEQ 64
#define NB   64

typedef __attribute__((ext_vector_type(8))) short  short8;
typedef __attribute__((ext_vector_type(4))) float  f32x4;
typedef __attribute__((ext_vector_type(2))) _Float16 h2;

__device__ __forceinline__ float bf(u16 v) {
    u32 u = ((u32)v) << 16;
    return __builtin_bit_cast(float, u);
}
__device__ __forceinline__ u16 f2b(float f) {
    u32 u = __builtin_bit_cast(u32, f);
    return (u16)((u + 0x7fffu + ((u >> 16) & 1u)) >> 16);  // RNE
}
__device__ __forceinline__ float lrelu(float x) { return x > 0.f ? x : 0.2f * x; }
__device__ __forceinline__ h2 i2h(int v) { return __builtin_bit_cast(h2, v); }
__device__ __forceinline__ float dot2(int hbits, int wbits, float acc) {
#if __has_builtin(__builtin_amdgcn_fdot2)
    return __builtin_amdgcn_fdot2(i2h(hbits), i2h(wbits), acc, false);
#else
    h2 a = i2h(hbits), b = i2h(wbits);
    return acc + (float)a.x * (float)b.x + (float)a.y * (float)b.y;
#endif
}
__device__ __forceinline__ float fsigm(float x) { return 1.f / (1.f + __expf(-x)); }
__device__ __forceinline__ float ftanh(float x) { return 1.f - 2.f / (__expf(2.f * x) + 1.f); }

#define NSEG 22
struct Segs { const void* src[NSEG]; int off[NSEG + 1]; int size[NSEG]; };

// ---- dtype sniff on lstm_k; also zeros scal ----
__global__ void sniff_kernel(const u16* __restrict__ probe, int* __restrict__ flag,
                             float* __restrict__ scal) {
    __shared__ int cnt[4];
    const int tid = threadIdx.x;
    int c = 0;
    for (int i = tid; i < 2048; i += 256) {
        u16 v = probe[2 * i];
        int e = (v >> 7) & 0xFF;
        if (v == 0 || (e >= 100 && e <= 130)) c++;
    }
    for (int off = 32; off; off >>= 1) c += __shfl_down(c, off, 64);
    if ((tid & 63) == 0) cnt[tid >> 6] = c;
    __syncthreads();
    if (tid == 0) {
        int t = cnt[0] + cnt[1] + cnt[2] + cnt[3];
        *flag = (t < 1024) ? 1 : 0;   // 1 = inputs are fp32
    }
    if (tid < 32) scal[tid] = 0.f;
}

// ---- canonicalize all float tensors into an fp32 arena ----
__global__ __launch_bounds__(256) void convert_kernel(Segs S, const int* __restrict__ flag,
                                                      float* __restrict__ arena) {
    const int gid = blockIdx.x * 256 + threadIdx.x;
    if (gid >= S.off[NSEG]) return;
    const int f32 = *flag;
    int s = 0;
    while (gid >= S.off[s + 1]) s++;
    const int i = gid - S.off[s];
    float v = 0.f;
    if (i < S.size[s])
        v = f32 ? ((const float*)S.src[s])[i] : bf(((const u16*)S.src[s])[i]);
    arena[gid] = v;
}

// ---- fused packing: Wr->f16; Wk/pimW/[pirW|vW] -> bf16 MFMA B-fragment order ----
__global__ __launch_bounds__(256) void pack_all(
    const void* __restrict__ Wr, const void* __restrict__ Wk,
    const void* __restrict__ Wpim, const void* __restrict__ Wpir,
    const void* __restrict__ Wv, const int* __restrict__ flag,
    u16* __restrict__ PF, u16* __restrict__ PBk, u16* __restrict__ PBpim,
    u16* __restrict__ PBpir)
{
    const int blk = blockIdx.x, tid = threadIdx.x;
    const int f32 = *flag;
    if (blk < 1024) {
        int gid = blk * 256 + tid;
        int k = gid >> 10, col = gid & 1023;
        float f = f32 ? ((const float*)Wr)[gid] : bf(((const u16*)Wr)[gid]);
        _Float16 h = (_Float16)f;
        PF[((size_t)(k >> 3) * 1024 + col) * 8 + (k & 7)] =
            __builtin_bit_cast(unsigned short, h);
    } else if (blk < 2048) {
        int gid = (blk - 1024) * 256 + tid;
        int k = gid >> 10, col = gid & 1023;
        u16 v = f32 ? f2b(((const float*)Wk)[gid]) : ((const u16*)Wk)[gid];
        PBk[((((size_t)(k >> 5) << 10) + col) * 4 + ((k >> 3) & 3)) * 8 + (k & 7)] = v;
    } else if (blk < 6144) {
        int gid = (blk - 2048) * 256 + tid;
        int k = gid >> 12, col = gid & 4095;
        u16 v = f32 ? f2b(((const float*)Wpim)[gid]) : ((const u16*)Wpim)[gid];
        PBpim[((((size_t)(k >> 5) << 12) + col) * 4 + ((k >> 3) & 3)) * 8 + (k & 7)] = v;
    } else {
        int gid = (blk - 6144) * 256 + tid;   // 16384 elems: 256 k x 64 cols
        int k = gid >> 6, col = gid & 63;
        u16 v = 0;
        if (col < 36)
            v = f32 ? f2b(((const float*)Wpir)[k * 36 + col]) : ((const u16*)Wpir)[k * 36 + col];
        else if (col == 36)
            v = f32 ? f2b(((const float*)Wv)[k]) : ((const u16*)Wv)[k];
        PBpir[(((size_t)(k >> 5) * 64 + col) * 4 + ((k >> 3) & 3)) * 8 + (k & 7)] = v;
    }
}

// ---- fused conv stack: one block per image; writes bf16 feat ----
__global__ __launch_bounds__(128) void conv_kernel(
    const float* __restrict__ x,
    const float* __restrict__ W1, const float* __restrict__ b1,
    const float* __restrict__ W2, const float* __restrict__ b2,
    const float* __restrict__ W3, const float* __restrict__ b3,
    const float* __restrict__ W4, const float* __restrict__ b4,
    u16* __restrict__ featbf)
{
    __shared__ float xs[832];
    __shared__ float c1[384];
    __shared__ float c2[480];
    __shared__ float c3[128];
    const int bt = blockIdx.x, tid = threadIdx.x;

    for (int i = tid; i < 832; i += 128) xs[i] = x[bt * 832 + i];
    __syncthreads();

    for (int idx = tid; idx < 384; idx += 128) {
        int oc = idx & 15, ow = (idx >> 4) & 3, oh = idx >> 6;
        float acc = b1[oc];
        for (int kh = 0; kh < 2; kh++)
            for (int kw = 0; kw < 2; kw++) {
                const float* xp = &xs[(2 * oh + kh) * 64 + (2 * ow + kw) * 8];
                const float* wp = &W1[((kh * 2 + kw) * 8) * 16 + oc];
                for (int ic = 0; ic < 8; ic++) acc += xp[ic] * wp[ic * 16];
            }
        c1[idx] = lrelu(acc);
    }
    __syncthreads();

    for (int idx = tid; idx < 480; idx += 128) {
        int oc = idx & 31, ow = (idx >> 5) % 3, oh = idx / 96;
        float acc = b2[oc];
        for (int kh = 0; kh < 2; kh++)
            for (int kw = 0; kw < 2; kw++) {
                const float* ip = &c1[((oh + kh) * 4 + (ow + kw)) * 16];
                const float* wp = &W2[((kh * 2 + kw) * 16) * 32 + oc];
                for (int ic = 0; ic < 16; ic++) acc += ip[ic] * wp[ic * 32];
            }
        c2[idx] = lrelu(acc);
    }
    __syncthreads();

    for (int idx = tid; idx < 128; idx += 128) {
        int oc = idx & 63, oh = idx >> 6;
        float acc = b3[oc];
        for (int kh = 0; kh < 2; kh++)
            for (int kw = 0; kw < 2; kw++) {
                const float* ip = &c2[((2 * oh + kh) * 3 + kw) * 32];
                const float* wp = &W3[((kh * 2 + kw) * 32) * 64 + oc];
                for (int ic = 0; ic < 32; ic++) acc += ip[ic] * wp[ic * 64];
            }
        c3[idx] = lrelu(acc);
    }
    __syncthreads();

    for (int idx = tid; idx < 256; idx += 128) {
        int oh = idx & 1, oc = idx >> 1;
        float acc = b4[oc];
        const float* ip = &c3[oh * 64];
        for (int ic = 0; ic < 64; ic++) acc += ip[ic] * W4[ic * 128 + oc];
        featbf[bt * 256 + idx] = f2b(lrelu(acc));
    }
}

// ---- MFMA GEMM: zx = featbf(4096x256) @ Wk + b : out f32 (4096x1024) ----
__global__ __launch_bounds__(256) void gemm_zx(
    const u16* __restrict__ Abf, const u16* __restrict__ PB,
    const float* __restrict__ bias, float* __restrict__ out)
{
    __shared__ __align__(16) u16 As[16 * 264];
    const int mb = blockIdx.y, nb = blockIdx.x, tid = threadIdx.x;
    const int m0 = mb * 16;
    {
        int row = tid >> 4, part = tid & 15;
        const f32x4* src = (const f32x4*)&Abf[(size_t)(m0 + row) * 256 + part * 16];
        f32x4 v0 = src[0], v1 = src[1];
        *(f32x4*)&As[row * 264 + part * 16] = v0;
        *(f32x4*)&As[row * 264 + part * 16 + 8] = v1;
    }
    __syncthreads();
    const int wv = tid >> 6, lane = tid & 63;
    const int colw = lane & 15, q = lane >> 4;
    const int n = nb * 64 + wv * 16 + colw;
    f32x4 acc = {0.f, 0.f, 0.f, 0.f};
#pragma unroll
    for (int kt = 0; kt < 8; kt++) {
        short8 a = *(const short8*)&As[colw * 264 + kt * 32 + q * 8];
        short8 b = *(const short8*)&PB[((((size_t)kt << 10) + n) * 4 + q) * 8];
        acc = __builtin_amdgcn_mfma_f32_16x16x32_bf16(a, b, acc, 0, 0, 0);
    }
    const float bj = bias[n];
#pragma unroll
    for (int r = 0; r < 4; r++) {
        int row = q * 4 + r;
        out[(size_t)(m0 + row) * 1024 + n] = acc[r] + bj;
    }
}

// ---- MFMA GEMM + fused masked-softmax partials for pim ----
__global__ __launch_bounds__(256) void gemm_pim(
    const u16* __restrict__ Abf, const u16* __restrict__ PB,
    const float* __restrict__ bias,
    const int* __restrict__ mask, const int* __restrict__ a_taken,
    float* __restrict__ partS, float* __restrict__ partU, float* __restrict__ za)
{
    __shared__ __align__(16) u16 As[16 * 264];
    __shared__ float redS[4][16], redU[4][16];
    const int mb = blockIdx.y, nb = blockIdx.x, tid = threadIdx.x;
    const int m0 = mb * 16;
    {
        int row = tid >> 4, part = tid & 15;
        const f32x4* src = (const f32x4*)&Abf[(size_t)(m0 + row) * 256 + part * 16];
        f32x4 v0 = src[0], v1 = src[1];
        *(f32x4*)&As[row * 264 + part * 16] = v0;
        *(f32x4*)&As[row * 264 + part * 16 + 8] = v1;
    }
    __syncthreads();
    const int wv = tid >> 6, lane = tid & 63;
    const int colw = lane & 15, q = lane >> 4;
    const int n = nb * 64 + wv * 16 + colw;
    f32x4 acc = {0.f, 0.f, 0.f, 0.f};
#pragma unroll
    for (int kt = 0; kt < 8; kt++) {
        short8 a = *(const short8*)&As[colw * 264 + kt * 32 + q * 8];
        short8 b = *(const short8*)&PB[((((size_t)kt << 12) + n) * 4 + q) * 8];
        acc = __builtin_amdgcn_mfma_f32_16x16x32_bf16(a, b, acc, 0, 0, 0);
    }
    const float bj = bias[n];
    float sv[4], uv[4];
#pragma unroll
    for (int r = 0; r < 4; r++) {
        int row = m0 + q * 4 + r;
        float z = acc[r] + bj;
        int m = mask[(size_t)row * 4096 + n];
        float e = __expf(z);
        sv[r] = m ? e : 0.f;
        uv[r] = m ? e * z : 0.f;
        if (n == a_taken[row]) za[row] = z;
    }
#pragma unroll
    for (int r = 0; r < 4; r++) {
        for (int off = 1; off < 16; off <<= 1) {
            sv[r] += __shfl_xor(sv[r], off, 16);
            uv[r] += __shfl_xor(uv[r], off, 16);
        }
        if (colw == 0) { redS[wv][q * 4 + r] = sv[r]; redU[wv][q * 4 + r] = uv[r]; }
    }
    __syncthreads();
    if (tid < 16) {
        float S = redS[0][tid] + redS[1][tid] + redS[2][tid] + redS[3][tid];
        float U = redU[0][tid] + redU[1][tid] + redU[2][tid] + redU[3][tid];
        partS[(size_t)(m0 + tid) * 64 + nb] = S;
        partU[(size_t)(m0 + tid) * 64 + nb] = U;
    }
}

// ---- MFMA pir head + vpred: 64 rows/block, fused softmax epilogue ----
__global__ __launch_bounds__(256) void gemm_pir(
    const u16* __restrict__ Abf, const u16* __restrict__ PB,
    const float* __restrict__ pir_b, const float* __restrict__ v_b,
    const int* __restrict__ a_taken,
    float* __restrict__ entpir, float* __restrict__ ppira, float* __restrict__ vpred)
{
    __shared__ __align__(16) u16 As[64 * 264];
    __shared__ float zbuf[64 * 65];
    const int blk = blockIdx.x, tid = threadIdx.x;
    const int m0 = blk * 64;
    // stage 64x256 A-tile: 1024 chunks of 16 contiguous u16 (FIX of R6 bug:
    // previous code strided f32x4 stores by 16 u16, leaving half of As uninit)
    for (int idx = tid; idx < 1024; idx += 256) {
        int row = idx >> 4, part = idx & 15;
        const f32x4* src = (const f32x4*)&Abf[(size_t)(m0 + row) * 256 + part * 16];
        f32x4 v0 = src[0], v1 = src[1];
        *(f32x4*)&As[row * 264 + part * 16] = v0;
        *(f32x4*)&As[row * 264 + part * 16 + 8] = v1;
    }
    __syncthreads();
    const int wv = tid >> 6, lane = tid & 63;
    const int colw = lane & 15, q = lane >> 4;
    f32x4 acc[4];
#pragma unroll
    for (int nt = 0; nt < 4; nt++) acc[nt] = (f32x4){0.f, 0.f, 0.f, 0.f};
#pragma unroll
    for (int kt = 0; kt < 8; kt++) {
        short8 a = *(const short8*)&As[(wv * 16 + colw) * 264 + kt * 32 + q * 8];
#pragma unroll
        for (int nt = 0; nt < 4; nt++) {
            short8 b = *(const short8*)&PB[((((size_t)kt * 64) + nt * 16 + colw) * 4 + q) * 8];
            acc[nt] = __builtin_amdgcn_mfma_f32_16x16x32_bf16(a, b, acc[nt], 0, 0, 0);
        }
    }
#pragma unroll
    for (int nt = 0; nt < 4; nt++) {
        int col = nt * 16 + colw;
        float bj = (col < 36) ? pir_b[col] : (col == 36 ? v_b[0] : 0.f);
#pragma unroll
        for (int r = 0; r < 4; r++)
            zbuf[(wv * 16 + q * 4 + r) * 65 + col] = acc[nt][r] + bj;
    }
    __syncthreads();
    if (lane < 16) {
        int rl = wv * 16 + lane;
        int R = m0 + rl;
        const float* zr = &zbuf[rl * 65];
        float Z = 0.f, U = 0.f;
        for (int c = 0; c < 36; c++) {
            float z = zr[c];
            float e = __expf(z);
            Z += e; U += e * z;
        }
        entpir[R] = logf(Z) - U / Z;
        ppira[R]  = __expf(zr[a_taken[R]]) / Z;
        vpred[R]  = zr[36];
    }
}

// ---- fold pim partials + GAE stats (merged) ----
__global__ __launch_bounds__(256) void pimfin_gae_kernel(
    const float* __restrict__ partS, const float* __restrict__ partU,
    const float* __restrict__ za,
    float* __restrict__ entpim, float* __restrict__ ppima,
    const float* __restrict__ g, float* __restrict__ scal)
{
    const int tid = threadIdx.x;
    if (blockIdx.x < 16) {
        const int r = blockIdx.x * 256 + tid;
        float S = 0.f, U = 0.f;
#pragma unroll
        for (int t = 0; t < 64; t++) { S += partS[(size_t)r * 64 + t]; U += partU[(size_t)r * 64 + t]; }
        entpim[r] = logf(S) - U / S;
        ppima[r]  = __expf(za[r]) / S;
    } else {
        float s = 0.f, s2 = 0.f;
        for (int i = tid; i < BT; i += 256) { float v = g[i]; s += v; s2 += v * v; }
        for (int off = 32; off; off >>= 1) { s += __shfl_down(s, off, 64); s2 += __shfl_down(s2, off, 64); }
        __shared__ float wsx[8];
        const int w = tid >> 6;
        if ((tid & 63) == 0) { wsx[w] = s; wsx[4 + w] = s2; }
        __syncthreads();
        if (tid == 0) {
            float S = 0.f, S2 = 0.f;
            for (int i = 0; i < 4; i++) { S += wsx[i]; S2 += wsx[4 + i]; }
            float mean = S / (float)BT;
            float var = S2 / (float)BT - mean * mean;
            scal[0] = mean;
            scal[1] = sqrtf(fmaxf(var, 0.f));
        }
    }
}

// ---- LSTM v5: resident weights (128-VGPR budget), LDS h-history, no in-loop
// global stores (barriers stop draining vmcnt), zx consumed late ----
#define NPRE 20
__global__ __launch_bounds__(1024, 4) void lstm_kernel(
    const float* __restrict__ zx, const u16* __restrict__ PF,
    u16* __restrict__ hseqbf)
{
    __shared__ float zp[1024];
    __shared__ __align__(16) u16 h16[256];
    __shared__ u16 hist[TSEQ * 256];        // 32 KB bf16 history
    const int b = blockIdx.x, tid = threadIdx.x;
    float c = 0.f;
    const int4* Pw = (const int4*)PF;

    int4 wr[NPRE];
#pragma unroll
    for (int j = 0; j < NPRE; j++) wr[j] = Pw[j * 1024 + tid];
    if (tid < 256) h16[tid] = 0;
    __syncthreads();

    for (int t = 0; t < TSEQ; t++) {
        float zxv = zx[(size_t)(b * TSEQ + t) * 1024 + tid];  // overlaps dot2 chain
        float acc0 = 0.f, acc1 = 0.f, acc2 = 0.f, acc3 = 0.f;
#pragma unroll
        for (int j = 0; j < NPRE; j++) {
            int4 hv = *(const int4*)&h16[j * 8];   // wave-uniform LDS broadcast
            acc0 = dot2(hv.x, wr[j].x, acc0);
            acc1 = dot2(hv.y, wr[j].y, acc1);
            acc2 = dot2(hv.z, wr[j].z, acc2);
            acc3 = dot2(hv.w, wr[j].w, acc3);
        }
#pragma unroll
        for (int j = NPRE; j < 32; j++) {
            int4 w = Pw[j * 1024 + tid];
            int4 hv = *(const int4*)&h16[j * 8];
            acc0 = dot2(hv.x, w.x, acc0);
            acc1 = dot2(hv.y, w.y, acc1);
            acc2 = dot2(hv.z, w.z, acc2);
            acc3 = dot2(hv.w, w.w, acc3);
        }
        zp[tid] = ((acc0 + acc1) + (acc2 + acc3)) + zxv;
        __syncthreads();           // gate pre-acts ready; h16 reads done
        if (tid < 256) {
            float ai = zp[tid], af = zp[256 + tid], ag = zp[512 + tid], ao = zp[768 + tid];
            float ig = fsigm(ai), fg = fsigm(af), og = fsigm(ao);
            float gg = ftanh(ag);
            c = fg * c + ig * gg;
            float h = og * ftanh(c);
            h16[tid] = __builtin_bit_cast(unsigned short, (_Float16)h);
            hist[t * 256 + tid] = f2b(h);
        }
        __syncthreads();           // new h16 visible
    }
    for (int i = tid; i < TSEQ * 256; i += 1024)
        hseqbf[(size_t)b * (TSEQ * 256) + i] = hist[i];
}

// ---- pg loss + entropy sums ----
__global__ __launch_bounds__(256) void pg_kernel(
    const float* __restrict__ ppira, const float* __restrict__ ppima,
    const float* __restrict__ entpir, const float* __restrict__ entpim,
    const float* __restrict__ lgold, const float* __restrict__ gae,
    float* __restrict__ scal)
{
    const int t = blockIdx.x * 256 + threadIdx.x;
    const float mean = scal[0], sd = scal[1];
    float p  = (t & 1) ? ppima[t] : ppira[t];
    float ln = logf(p);
    float rt = __expf(ln - lgold[t]);
    float g  = (gae[t] - mean) / (sd + 1e-8f);
    float rtc = fminf(fmaxf(rt, 0.8f), 1.2f);
    float pg = fmaxf(-g * rt, -g * rtc);
    float e1 = entpir[t], e2 = entpim[t];
    for (int off = 32; off; off >>= 1) {
        pg += __shfl_down(pg, off, 64);
        e1 += __shfl_down(e1, off, 64);
        e2 += __shfl_down(e2, off, 64);
    }
    if ((threadIdx.x & 63) == 0) {
        atomicAdd(&scal[2], pg);
        atomicAdd(&scal[3], e1 + e2);
    }
}

// ---- vf loss: faithful (BT,BT) broadcast ----
__global__ __launch_bounds__(256) void vf_kernel(
    const float* __restrict__ vpred, const float* __restrict__ ovp,
    const float* __restrict__ ret, float* __restrict__ scal)
{
    const int i = blockIdx.x;
    const float vp = vpred[i];
    float s = 0.f;
    for (int j = threadIdx.x; j < BT; j += 256) {
        float r = ret[j], o = ovp[j];
        float d = fminf(fmaxf(vp - o, -0.2f), 0.2f);
        float v1 = vp - r;     v1 *= v1;
        float v2 = o + d - r;  v2 *= v2;
        s += fmaxf(v1, v2);
    }
    for (int off = 32; off; off >>= 1) s += __shfl_down(s, off, 64);
    __shared__ float wsum[4];
    if ((threadIdx.x & 63) == 0) wsum[threadIdx.x >> 6] = s;
    __syncthreads();
    if (threadIdx.x == 0) atomicAdd(&scal[5], wsum[0] + wsum[1] + wsum[2] + wsum[3]);
}

// ---- finalize ----
__global__ void fin_kernel(const float* __restrict__ scal, const int* __restrict__ flag,
                           void* __restrict__ out) {
    float pg  = scal[2] / (float)BT;
    float ent = scal[3];
    float vf  = 0.5f * scal[5] / ((float)BT * (float)BT);
    float loss = pg - ent + vf;
    if (*flag) {
        float* o = (float*)out;
        o[0] = loss; o[1] = pg; o[2] = ent; o[3] = vf;
    } else {
        u16* o = (u16*)out;
        o[0] = f2b(loss); o[1] = f2b(pg); o[2] = f2b(ent); o[3] = f2b(vf);
    }
}

extern "C" void kernel_launch(void* const* d_in, const int* in_sizes, int n_in,
                              void* d_out, int out_size, void* d_ws, size_t ws_size,
                              hipStream_t stream)
{
    const int* mask = (const int*)d_in[1];
    const int* a_tk = (const int*)d_in[3];

    static const int sz[NSEG]  = {3407872, 4096, 4096, 4096, 4096, 512, 16, 2048, 32,
                                  8192, 64, 8192, 128, 262144, 262144, 1024,
                                  9216, 36, 1048576, 4096, 256, 1};
    static const int din[NSEG] = {0, 2, 4, 5, 6, 7, 8, 9, 10, 11, 12, 13, 14,
                                  15, 16, 17, 18, 19, 20, 21, 22, 23};
    Segs S;
    int off = 0;
    for (int s = 0; s < NSEG; s++) {
        S.src[s] = d_in[din[s]];
        S.off[s] = off;
        S.size[s] = sz[s];
        off += (sz[s] + 3) & ~3;
    }
    S.off[NSEG] = off;

    float* arena = (float*)d_ws;
    const float* xa    = arena + S.off[0];
    const float* lgold = arena + S.off[1];
    const float* gae   = arena + S.off[2];
    const float* ovp   = arena + S.off[3];
    const float* ret   = arena + S.off[4];
    const float* W1 = arena + S.off[5],  *b1 = arena + S.off[6];
    const float* W2 = arena + S.off[7],  *b2 = arena + S.off[8];
    const float* W3 = arena + S.off[9],  *b3 = arena + S.off[10];
    const float* W4 = arena + S.off[11], *b4 = arena + S.off[12];
    const float* lb = arena + S.off[15];
    const float* pirB = arena + S.off[17];
    const float* pimB = arena + S.off[19];
    const float* vB   = arena + S.off[21];

    // scratch after arena
    float* p = arena + off;
    u16*   featbf = (u16*)p;            p += 524288;    // 1M u16
    float* zx     = p;                  p += 4194304;
    u16*   hseqbf = (u16*)p;            p += 524288;    // 1M u16
    u16*   PF     = (u16*)p;            p += 131072;    // f16 Wr
    u16*   PBk    = (u16*)p;            p += 131072;    // bf16 Wk frag
    u16*   PBpim  = (u16*)p;            p += 524288;    // bf16 pimW frag
    u16*   PBpir  = (u16*)p;            p += 8192;      // bf16 [pirW|vW] frag
    float* scal   = p;                  p += 32;
    int*   flag   = (int*)p;

    // alias small post-conv buffers onto the x-arena region (x consumed by conv)
    float* q = (float*)(arena + S.off[0]);
    float* partS  = q;                  q += 262144;
    float* partU  = q;                  q += 262144;
    float* za     = q;                  q += 4096;
    float* entpir = q;                  q += 4096;
    float* entpim = q;                  q += 4096;
    float* ppira  = q;                  q += 4096;
    float* ppima  = q;                  q += 4096;
    float* vpred  = q;                  q += 4096;

    sniff_kernel<<<1, 256, 0, stream>>>((const u16*)d_in[15], flag, scal);
    convert_kernel<<<(S.off[NSEG] + 255) / 256, 256, 0, stream>>>(S, flag, arena);
    pack_all<<<6208, 256, 0, stream>>>(d_in[16], d_in[15], d_in[20], d_in[18],
                                       d_in[22], flag, PF, PBk, PBpim, PBpir);
    conv_kernel<<<BT, 128, 0, stream>>>(xa, W1, b1, W2, b2, W3, b3, W4, b4, featbf);
    gemm_zx<<<dim3(16, 256), 256, 0, stream>>>(featbf, PBk, lb, zx);
    lstm_kernel<<<NB, 1024, 0, stream>>>(zx, PF, hseqbf);
    gemm_pir<<<64, 256, 0, stream>>>(hseqbf, PBpir, pirB, vB, a_tk, entpir, ppira, vpred);
    gemm_pim<<<dim3(64, 256), 256, 0, stream>>>(hseqbf, PBpim, pimB, mask, a_tk, partS, partU, za);
    pimfin_gae_kernel<<<17, 256, 0, stream>>>(partS, partU, za, entpim, ppima, gae, scal);
    pg_kernel<<<16, 256, 0, stream>>>(ppira, ppima, entpir, entpim, lgold, gae, scal);
    vf_kernel<<<BT, 256, 0, stream>>>(vpred, ovp, ret, scal);
    fin_kernel<<<1, 1, 0, stream>>>(scal, flag, (u16*)d_out);
}

// Round 8
// 570.814 us; speedup vs baseline: 2.8245x; 1.0166x over previous
//
#include <hip/hip_runtime.h>

typedef unsigned short u16;
typedef unsigned int   u32;

#define BT   4096
#define TSEQ 64
#define NB   64

typedef __attribute__((ext_vector_type(8))) short  short8;
typedef __attribute__((ext_vector_type(4))) float  f32x4;
typedef __attribute__((ext_vector_type(2))) _Float16 h2;

__device__ __forceinline__ float bf(u16 v) {
    u32 u = ((u32)v) << 16;
    return __builtin_bit_cast(float, u);
}
__device__ __forceinline__ u16 f2b(float f) {
    u32 u = __builtin_bit_cast(u32, f);
    return (u16)((u + 0x7fffu + ((u >> 16) & 1u)) >> 16);  // RNE
}
__device__ __forceinline__ float lrelu(float x) { return x > 0.f ? x : 0.2f * x; }
__device__ __forceinline__ h2 i2h(int v) { return __builtin_bit_cast(h2, v); }
__device__ __forceinline__ float dot2(int hbits, int wbits, float acc) {
#if __has_builtin(__builtin_amdgcn_fdot2)
    return __builtin_amdgcn_fdot2(i2h(hbits), i2h(wbits), acc, false);
#else
    h2 a = i2h(hbits), b = i2h(wbits);
    return acc + (float)a.x * (float)b.x + (float)a.y * (float)b.y;
#endif
}
__device__ __forceinline__ float fsigm(float x) { return 1.f / (1.f + __expf(-x)); }
__device__ __forceinline__ float ftanh(float x) { return 1.f - 2.f / (__expf(2.f * x) + 1.f); }

#define NSEG 22
struct Segs { const void* src[NSEG]; int off[NSEG + 1]; int size[NSEG]; };

// ---- dtype sniff on lstm_k; also zeros scal ----
__global__ void sniff_kernel(const u16* __restrict__ probe, int* __restrict__ flag,
                             float* __restrict__ scal) {
    __shared__ int cnt[4];
    const int tid = threadIdx.x;
    int c = 0;
    for (int i = tid; i < 2048; i += 256) {
        u16 v = probe[2 * i];
        int e = (v >> 7) & 0xFF;
        if (v == 0 || (e >= 100 && e <= 130)) c++;
    }
    for (int off = 32; off; off >>= 1) c += __shfl_down(c, off, 64);
    if ((tid & 63) == 0) cnt[tid >> 6] = c;
    __syncthreads();
    if (tid == 0) {
        int t = cnt[0] + cnt[1] + cnt[2] + cnt[3];
        *flag = (t < 1024) ? 1 : 0;   // 1 = inputs are fp32
    }
    if (tid < 32) scal[tid] = 0.f;
}

// ---- canonicalize all float tensors into an fp32 arena ----
__global__ __launch_bounds__(256) void convert_kernel(Segs S, const int* __restrict__ flag,
                                                      float* __restrict__ arena) {
    const int gid = blockIdx.x * 256 + threadIdx.x;
    if (gid >= S.off[NSEG]) return;
    const int f32 = *flag;
    int s = 0;
    while (gid >= S.off[s + 1]) s++;
    const int i = gid - S.off[s];
    float v = 0.f;
    if (i < S.size[s])
        v = f32 ? ((const float*)S.src[s])[i] : bf(((const u16*)S.src[s])[i]);
    arena[gid] = v;
}

// ---- fused packing: Wr->f16; Wk/pimW/[pirW|vW] -> bf16 MFMA B-fragment order ----
__global__ __launch_bounds__(256) void pack_all(
    const void* __restrict__ Wr, const void* __restrict__ Wk,
    const void* __restrict__ Wpim, const void* __restrict__ Wpir,
    const void* __restrict__ Wv, const int* __restrict__ flag,
    u16* __restrict__ PF, u16* __restrict__ PBk, u16* __restrict__ PBpim,
    u16* __restrict__ PBpir)
{
    const int blk = blockIdx.x, tid = threadIdx.x;
    const int f32 = *flag;
    if (blk < 1024) {
        int gid = blk * 256 + tid;
        int k = gid >> 10, col = gid & 1023;
        float f = f32 ? ((const float*)Wr)[gid] : bf(((const u16*)Wr)[gid]);
        _Float16 h = (_Float16)f;
        PF[((size_t)(k >> 3) * 1024 + col) * 8 + (k & 7)] =
            __builtin_bit_cast(unsigned short, h);
    } else if (blk < 2048) {
        int gid = (blk - 1024) * 256 + tid;
        int k = gid >> 10, col = gid & 1023;
        u16 v = f32 ? f2b(((const float*)Wk)[gid]) : ((const u16*)Wk)[gid];
        PBk[((((size_t)(k >> 5) << 10) + col) * 4 + ((k >> 3) & 3)) * 8 + (k & 7)] = v;
    } else if (blk < 6144) {
        int gid = (blk - 2048) * 256 + tid;
        int k = gid >> 12, col = gid & 4095;
        u16 v = f32 ? f2b(((const float*)Wpim)[gid]) : ((const u16*)Wpim)[gid];
        PBpim[((((size_t)(k >> 5) << 12) + col) * 4 + ((k >> 3) & 3)) * 8 + (k & 7)] = v;
    } else {
        int gid = (blk - 6144) * 256 + tid;   // 16384 elems: 256 k x 64 cols
        int k = gid >> 6, col = gid & 63;
        u16 v = 0;
        if (col < 36)
            v = f32 ? f2b(((const float*)Wpir)[k * 36 + col]) : ((const u16*)Wpir)[k * 36 + col];
        else if (col == 36)
            v = f32 ? f2b(((const float*)Wv)[k]) : ((const u16*)Wv)[k];
        PBpir[(((size_t)(k >> 5) * 64 + col) * 4 + ((k >> 3) & 3)) * 8 + (k & 7)] = v;
    }
}

// ---- fused conv stack: one block per image; writes bf16 feat ----
__global__ __launch_bounds__(128) void conv_kernel(
    const float* __restrict__ x,
    const float* __restrict__ W1, const float* __restrict__ b1,
    const float* __restrict__ W2, const float* __restrict__ b2,
    const float* __restrict__ W3, const float* __restrict__ b3,
    const float* __restrict__ W4, const float* __restrict__ b4,
    u16* __restrict__ featbf)
{
    __shared__ float xs[832];
    __shared__ float c1[384];
    __shared__ float c2[480];
    __shared__ float c3[128];
    const int bt = blockIdx.x, tid = threadIdx.x;

    for (int i = tid; i < 832; i += 128) xs[i] = x[bt * 832 + i];
    __syncthreads();

    for (int idx = tid; idx < 384; idx += 128) {
        int oc = idx & 15, ow = (idx >> 4) & 3, oh = idx >> 6;
        float acc = b1[oc];
        for (int kh = 0; kh < 2; kh++)
            for (int kw = 0; kw < 2; kw++) {
                const float* xp = &xs[(2 * oh + kh) * 64 + (2 * ow + kw) * 8];
                const float* wp = &W1[((kh * 2 + kw) * 8) * 16 + oc];
                for (int ic = 0; ic < 8; ic++) acc += xp[ic] * wp[ic * 16];
            }
        c1[idx] = lrelu(acc);
    }
    __syncthreads();

    for (int idx = tid; idx < 480; idx += 128) {
        int oc = idx & 31, ow = (idx >> 5) % 3, oh = idx / 96;
        float acc = b2[oc];
        for (int kh = 0; kh < 2; kh++)
            for (int kw = 0; kw < 2; kw++) {
                const float* ip = &c1[((oh + kh) * 4 + (ow + kw)) * 16];
                const float* wp = &W2[((kh * 2 + kw) * 16) * 32 + oc];
                for (int ic = 0; ic < 16; ic++) acc += ip[ic] * wp[ic * 32];
            }
        c2[idx] = lrelu(acc);
    }
    __syncthreads();

    for (int idx = tid; idx < 128; idx += 128) {
        int oc = idx & 63, oh = idx >> 6;
        float acc = b3[oc];
        for (int kh = 0; kh < 2; kh++)
            for (int kw = 0; kw < 2; kw++) {
                const float* ip = &c2[((2 * oh + kh) * 3 + kw) * 32];
                const float* wp = &W3[((kh * 2 + kw) * 32) * 64 + oc];
                for (int ic = 0; ic < 32; ic++) acc += ip[ic] * wp[ic * 64];
            }
        c3[idx] = lrelu(acc);
    }
    __syncthreads();

    for (int idx = tid; idx < 256; idx += 128) {
        int oh = idx & 1, oc = idx >> 1;
        float acc = b4[oc];
        const float* ip = &c3[oh * 64];
        for (int ic = 0; ic < 64; ic++) acc += ip[ic] * W4[ic * 128 + oc];
        featbf[bt * 256 + idx] = f2b(lrelu(acc));
    }
}

// ---- MFMA GEMM: zx = featbf(4096x256) @ Wk + b : out f32 (4096x1024) ----
__global__ __launch_bounds__(256) void gemm_zx(
    const u16* __restrict__ Abf, const u16* __restrict__ PB,
    const float* __restrict__ bias, float* __restrict__ out)
{
    __shared__ __align__(16) u16 As[16 * 264];
    const int mb = blockIdx.y, nb = blockIdx.x, tid = threadIdx.x;
    const int m0 = mb * 16;
    {
        int row = tid >> 4, part = tid & 15;
        const f32x4* src = (const f32x4*)&Abf[(size_t)(m0 + row) * 256 + part * 16];
        f32x4 v0 = src[0], v1 = src[1];
        *(f32x4*)&As[row * 264 + part * 16] = v0;
        *(f32x4*)&As[row * 264 + part * 16 + 8] = v1;
    }
    __syncthreads();
    const int wv = tid >> 6, lane = tid & 63;
    const int colw = lane & 15, q = lane >> 4;
    const int n = nb * 64 + wv * 16 + colw;
    f32x4 acc = {0.f, 0.f, 0.f, 0.f};
#pragma unroll
    for (int kt = 0; kt < 8; kt++) {
        short8 a = *(const short8*)&As[colw * 264 + kt * 32 + q * 8];
        short8 b = *(const short8*)&PB[((((size_t)kt << 10) + n) * 4 + q) * 8];
        acc = __builtin_amdgcn_mfma_f32_16x16x32_bf16(a, b, acc, 0, 0, 0);
    }
    const float bj = bias[n];
#pragma unroll
    for (int r = 0; r < 4; r++) {
        int row = q * 4 + r;
        out[(size_t)(m0 + row) * 1024 + n] = acc[r] + bj;
    }
}

// ---- MFMA GEMM + fused masked-softmax partials for pim ----
__global__ __launch_bounds__(256) void gemm_pim(
    const u16* __restrict__ Abf, const u16* __restrict__ PB,
    const float* __restrict__ bias,
    const int* __restrict__ mask, const int* __restrict__ a_taken,
    float* __restrict__ partS, float* __restrict__ partU, float* __restrict__ za)
{
    __shared__ __align__(16) u16 As[16 * 264];
    __shared__ float redS[4][16], redU[4][16];
    const int mb = blockIdx.y, nb = blockIdx.x, tid = threadIdx.x;
    const int m0 = mb * 16;
    {
        int row = tid >> 4, part = tid & 15;
        const f32x4* src = (const f32x4*)&Abf[(size_t)(m0 + row) * 256 + part * 16];
        f32x4 v0 = src[0], v1 = src[1];
        *(f32x4*)&As[row * 264 + part * 16] = v0;
        *(f32x4*)&As[row * 264 + part * 16 + 8] = v1;
    }
    __syncthreads();
    const int wv = tid >> 6, lane = tid & 63;
    const int colw = lane & 15, q = lane >> 4;
    const int n = nb * 64 + wv * 16 + colw;
    f32x4 acc = {0.f, 0.f, 0.f, 0.f};
#pragma unroll
    for (int kt = 0; kt < 8; kt++) {
        short8 a = *(const short8*)&As[colw * 264 + kt * 32 + q * 8];
        short8 b = *(const short8*)&PB[((((size_t)kt << 12) + n) * 4 + q) * 8];
        acc = __builtin_amdgcn_mfma_f32_16x16x32_bf16(a, b, acc, 0, 0, 0);
    }
    const float bj = bias[n];
    float sv[4], uv[4];
#pragma unroll
    for (int r = 0; r < 4; r++) {
        int row = m0 + q * 4 + r;
        float z = acc[r] + bj;
        int m = mask[(size_t)row * 4096 + n];
        float e = __expf(z);
        sv[r] = m ? e : 0.f;
        uv[r] = m ? e * z : 0.f;
        if (n == a_taken[row]) za[row] = z;
    }
#pragma unroll
    for (int r = 0; r < 4; r++) {
        for (int off = 1; off < 16; off <<= 1) {
            sv[r] += __shfl_xor(sv[r], off, 16);
            uv[r] += __shfl_xor(uv[r], off, 16);
        }
        if (colw == 0) { redS[wv][q * 4 + r] = sv[r]; redU[wv][q * 4 + r] = uv[r]; }
    }
    __syncthreads();
    if (tid < 16) {
        float S = redS[0][tid] + redS[1][tid] + redS[2][tid] + redS[3][tid];
        float U = redU[0][tid] + redU[1][tid] + redU[2][tid] + redU[3][tid];
        partS[(size_t)(m0 + tid) * 64 + nb] = S;
        partU[(size_t)(m0 + tid) * 64 + nb] = U;
    }
}

// ---- MFMA pir head + vpred: 64 rows/block, fused softmax epilogue ----
__global__ __launch_bounds__(256) void gemm_pir(
    const u16* __restrict__ Abf, const u16* __restrict__ PB,
    const float* __restrict__ pir_b, const float* __restrict__ v_b,
    const int* __restrict__ a_taken,
    float* __restrict__ entpir, float* __restrict__ ppira, float* __restrict__ vpred)
{
    __shared__ __align__(16) u16 As[64 * 264];
    __shared__ float zbuf[64 * 65];
    const int blk = blockIdx.x, tid = threadIdx.x;
    const int m0 = blk * 64;
    for (int idx = tid; idx < 1024; idx += 256) {
        int row = idx >> 4, part = idx & 15;
        const f32x4* src = (const f32x4*)&Abf[(size_t)(m0 + row) * 256 + part * 16];
        f32x4 v0 = src[0], v1 = src[1];
        *(f32x4*)&As[row * 264 + part * 16] = v0;
        *(f32x4*)&As[row * 264 + part * 16 + 8] = v1;
    }
    __syncthreads();
    const int wv = tid >> 6, lane = tid & 63;
    const int colw = lane & 15, q = lane >> 4;
    f32x4 acc[4];
#pragma unroll
    for (int nt = 0; nt < 4; nt++) acc[nt] = (f32x4){0.f, 0.f, 0.f, 0.f};
#pragma unroll
    for (int kt = 0; kt < 8; kt++) {
        short8 a = *(const short8*)&As[(wv * 16 + colw) * 264 + kt * 32 + q * 8];
#pragma unroll
        for (int nt = 0; nt < 4; nt++) {
            short8 b = *(const short8*)&PB[((((size_t)kt * 64) + nt * 16 + colw) * 4 + q) * 8];
            acc[nt] = __builtin_amdgcn_mfma_f32_16x16x32_bf16(a, b, acc[nt], 0, 0, 0);
        }
    }
#pragma unroll
    for (int nt = 0; nt < 4; nt++) {
        int col = nt * 16 + colw;
        float bj = (col < 36) ? pir_b[col] : (col == 36 ? v_b[0] : 0.f);
#pragma unroll
        for (int r = 0; r < 4; r++)
            zbuf[(wv * 16 + q * 4 + r) * 65 + col] = acc[nt][r] + bj;
    }
    __syncthreads();
    if (lane < 16) {
        int rl = wv * 16 + lane;
        int R = m0 + rl;
        const float* zr = &zbuf[rl * 65];
        float Z = 0.f, U = 0.f;
        for (int c = 0; c < 36; c++) {
            float z = zr[c];
            float e = __expf(z);
            Z += e; U += e * z;
        }
        entpir[R] = logf(Z) - U / Z;
        ppira[R]  = __expf(zr[a_taken[R]]) / Z;
        vpred[R]  = zr[36];
    }
}

// ---- fold pim partials + GAE stats (merged) ----
__global__ __launch_bounds__(256) void pimfin_gae_kernel(
    const float* __restrict__ partS, const float* __restrict__ partU,
    const float* __restrict__ za,
    float* __restrict__ entpim, float* __restrict__ ppima,
    const float* __restrict__ g, float* __restrict__ scal)
{
    const int tid = threadIdx.x;
    if (blockIdx.x < 16) {
        const int r = blockIdx.x * 256 + tid;
        float S = 0.f, U = 0.f;
#pragma unroll
        for (int t = 0; t < 64; t++) { S += partS[(size_t)r * 64 + t]; U += partU[(size_t)r * 64 + t]; }
        entpim[r] = logf(S) - U / S;
        ppima[r]  = __expf(za[r]) / S;
    } else {
        float s = 0.f, s2 = 0.f;
        for (int i = tid; i < BT; i += 256) { float v = g[i]; s += v; s2 += v * v; }
        for (int off = 32; off; off >>= 1) { s += __shfl_down(s, off, 64); s2 += __shfl_down(s2, off, 64); }
        __shared__ float wsx[8];
        const int w = tid >> 6;
        if ((tid & 63) == 0) { wsx[w] = s; wsx[4 + w] = s2; }
        __syncthreads();
        if (tid == 0) {
            float S = 0.f, S2 = 0.f;
            for (int i = 0; i < 4; i++) { S += wsx[i]; S2 += wsx[4 + i]; }
            float mean = S / (float)BT;
            float var = S2 / (float)BT - mean * mean;
            scal[0] = mean;
            scal[1] = sqrtf(fmaxf(var, 0.f));
        }
    }
}

// ---- LSTM v6: LDS padded >80KB so only 1 block/CU fits -> compiler loses the
// 64-VGPR/2-block occupancy incentive and can keep NPRE chunks truly resident
// under the 128-VGPR cap of __launch_bounds__(1024,4). Streamed loads issued
// first so vmcnt overlaps the resident dot2 chain. ----
#define NPRE 20
#define NSTREAM (32 - NPRE)
__global__ __launch_bounds__(1024, 4) void lstm_kernel(
    const float* __restrict__ zx, const u16* __restrict__ PF,
    u16* __restrict__ hseqbf)
{
    __shared__ float zp[1024];
    __shared__ __align__(16) u16 h16[256];
    // 96 KB: first TSEQ*256 entries used as history; the 2x tail is padding to
    // force 1 block/CU (see header comment). Same array so it can't be elided.
    __shared__ u16 hist[TSEQ * 256 * 3];
    const int b = blockIdx.x, tid = threadIdx.x;
    float c = 0.f;
    const int4* Pw = (const int4*)PF;

    int4 wr[NPRE];
#pragma unroll
    for (int j = 0; j < NPRE; j++) wr[j] = Pw[j * 1024 + tid];
    if (tid < 256) h16[tid] = 0;
    __syncthreads();

    for (int t = 0; t < TSEQ; t++) {
        // issue streamed loads first (latency overlapped by resident dot2s)
        int4 ws[NSTREAM];
#pragma unroll
        for (int j = 0; j < NSTREAM; j++) ws[j] = Pw[(NPRE + j) * 1024 + tid];
        float zxv = zx[(size_t)(b * TSEQ + t) * 1024 + tid];

        float acc0 = 0.f, acc1 = 0.f, acc2 = 0.f, acc3 = 0.f;
#pragma unroll
        for (int j = 0; j < NPRE; j++) {
            int4 hv = *(const int4*)&h16[j * 8];   // wave-uniform LDS broadcast
            acc0 = dot2(hv.x, wr[j].x, acc0);
            acc1 = dot2(hv.y, wr[j].y, acc1);
            acc2 = dot2(hv.z, wr[j].z, acc2);
            acc3 = dot2(hv.w, wr[j].w, acc3);
        }
#pragma unroll
        for (int j = 0; j < NSTREAM; j++) {
            int4 hv = *(const int4*)&h16[(NPRE + j) * 8];
            acc0 = dot2(hv.x, ws[j].x, acc0);
            acc1 = dot2(hv.y, ws[j].y, acc1);
            acc2 = dot2(hv.z, ws[j].z, acc2);
            acc3 = dot2(hv.w, ws[j].w, acc3);
        }
        zp[tid] = ((acc0 + acc1) + (acc2 + acc3)) + zxv;
        __syncthreads();           // gate pre-acts ready; h16 reads done
        if (tid < 256) {
            float ai = zp[tid], af = zp[256 + tid], ag = zp[512 + tid], ao = zp[768 + tid];
            float ig = fsigm(ai), fg = fsigm(af), og = fsigm(ao);
            float gg = ftanh(ag);
            c = fg * c + ig * gg;
            float h = og * ftanh(c);
            h16[tid] = __builtin_bit_cast(unsigned short, (_Float16)h);
            hist[t * 256 + tid] = f2b(h);
        }
        __syncthreads();           // new h16 visible
    }
    for (int i = tid; i < TSEQ * 256; i += 1024)
        hseqbf[(size_t)b * (TSEQ * 256) + i] = hist[i];
}

// ---- pg loss + entropy sums ----
__global__ __launch_bounds__(256) void pg_kernel(
    const float* __restrict__ ppira, const float* __restrict__ ppima,
    const float* __restrict__ entpir, const float* __restrict__ entpim,
    const float* __restrict__ lgold, const float* __restrict__ gae,
    float* __restrict__ scal)
{
    const int t = blockIdx.x * 256 + threadIdx.x;
    const float mean = scal[0], sd = scal[1];
    float p  = (t & 1) ? ppima[t] : ppira[t];
    float ln = logf(p);
    float rt = __expf(ln - lgold[t]);
    float g  = (gae[t] - mean) / (sd + 1e-8f);
    float rtc = fminf(fmaxf(rt, 0.8f), 1.2f);
    float pg = fmaxf(-g * rt, -g * rtc);
    float e1 = entpir[t], e2 = entpim[t];
    for (int off = 32; off; off >>= 1) {
        pg += __shfl_down(pg, off, 64);
        e1 += __shfl_down(e1, off, 64);
        e2 += __shfl_down(e2, off, 64);
    }
    if ((threadIdx.x & 63) == 0) {
        atomicAdd(&scal[2], pg);
        atomicAdd(&scal[3], e1 + e2);
    }
}

// ---- vf loss: faithful (BT,BT) broadcast ----
__global__ __launch_bounds__(256) void vf_kernel(
    const float* __restrict__ vpred, const float* __restrict__ ovp,
    const float* __restrict__ ret, float* __restrict__ scal)
{
    const int i = blockIdx.x;
    const float vp = vpred[i];
    float s = 0.f;
    for (int j = threadIdx.x; j < BT; j += 256) {
        float r = ret[j], o = ovp[j];
        float d = fminf(fmaxf(vp - o, -0.2f), 0.2f);
        float v1 = vp - r;     v1 *= v1;
        float v2 = o + d - r;  v2 *= v2;
        s += fmaxf(v1, v2);
    }
    for (int off = 32; off; off >>= 1) s += __shfl_down(s, off, 64);
    __shared__ float wsum[4];
    if ((threadIdx.x & 63) == 0) wsum[threadIdx.x >> 6] = s;
    __syncthreads();
    if (threadIdx.x == 0) atomicAdd(&scal[5], wsum[0] + wsum[1] + wsum[2] + wsum[3]);
}

// ---- finalize ----
__global__ void fin_kernel(const float* __restrict__ scal, const int* __restrict__ flag,
                           void* __restrict__ out) {
    float pg  = scal[2] / (float)BT;
    float ent = scal[3];
    float vf  = 0.5f * scal[5] / ((float)BT * (float)BT);
    float loss = pg - ent + vf;
    if (*flag) {
        float* o = (float*)out;
        o[0] = loss; o[1] = pg; o[2] = ent; o[3] = vf;
    } else {
        u16* o = (u16*)out;
        o[0] = f2b(loss); o[1] = f2b(pg); o[2] = f2b(ent); o[3] = f2b(vf);
    }
}

extern "C" void kernel_launch(void* const* d_in, const int* in_sizes, int n_in,
                              void* d_out, int out_size, void* d_ws, size_t ws_size,
                              hipStream_t stream)
{
    const int* mask = (const int*)d_in[1];
    const int* a_tk = (const int*)d_in[3];

    static const int sz[NSEG]  = {3407872, 4096, 4096, 4096, 4096, 512, 16, 2048, 32,
                                  8192, 64, 8192, 128, 262144, 262144, 1024,
                                  9216, 36, 1048576, 4096, 256, 1};
    static const int din[NSEG] = {0, 2, 4, 5, 6, 7, 8, 9, 10, 11, 12, 13, 14,
                                  15, 16, 17, 18, 19, 20, 21, 22, 23};
    Segs S;
    int off = 0;
    for (int s = 0; s < NSEG; s++) {
        S.src[s] = d_in[din[s]];
        S.off[s] = off;
        S.size[s] = sz[s];
        off += (sz[s] + 3) & ~3;
    }
    S.off[NSEG] = off;

    float* arena = (float*)d_ws;
    const float* xa    = arena + S.off[0];
    const float* lgold = arena + S.off[1];
    const float* gae   = arena + S.off[2];
    const float* ovp   = arena + S.off[3];
    const float* ret   = arena + S.off[4];
    const float* W1 = arena + S.off[5],  *b1 = arena + S.off[6];
    const float* W2 = arena + S.off[7],  *b2 = arena + S.off[8];
    const float* W3 = arena + S.off[9],  *b3 = arena + S.off[10];
    const float* W4 = arena + S.off[11], *b4 = arena + S.off[12];
    const float* lb = arena + S.off[15];
    const float* pirB = arena + S.off[17];
    const float* pimB = arena + S.off[19];
    const float* vB   = arena + S.off[21];

    // scratch after arena
    float* p = arena + off;
    u16*   featbf = (u16*)p;            p += 524288;    // 1M u16
    float* zx     = p;                  p += 4194304;
    u16*   hseqbf = (u16*)p;            p += 524288;    // 1M u16
    u16*   PF     = (u16*)p;            p += 131072;    // f16 Wr
    u16*   PBk    = (u16*)p;            p += 131072;    // bf16 Wk frag
    u16*   PBpim  = (u16*)p;            p += 524288;    // bf16 pimW frag
    u16*   PBpir  = (u16*)p;            p += 8192;      // bf16 [pirW|vW] frag
    float* scal   = p;                  p += 32;
    int*   flag   = (int*)p;

    // alias small post-conv buffers onto the x-arena region (x consumed by conv)
    float* q = (float*)(arena + S.off[0]);
    float* partS  = q;                  q += 262144;
    float* partU  = q;                  q += 262144;
    float* za     = q;                  q += 4096;
    float* entpir = q;                  q += 4096;
    float* entpim = q;                  q += 4096;
    float* ppira  = q;                  q += 4096;
    float* ppima  = q;                  q += 4096;
    float* vpred  = q;                  q += 4096;

    sniff_kernel<<<1, 256, 0, stream>>>((const u16*)d_in[15], flag, scal);
    convert_kernel<<<(S.off[NSEG] + 255) / 256, 256, 0, stream>>>(S, flag, arena);
    pack_all<<<6208, 256, 0, stream>>>(d_in[16], d_in[15], d_in[20], d_in[18],
                                       d_in[22], flag, PF, PBk, PBpim, PBpir);
    conv_kernel<<<BT, 128, 0, stream>>>(xa, W1, b1, W2, b2, W3, b3, W4, b4, featbf);
    gemm_zx<<<dim3(16, 256), 256, 0, stream>>>(featbf, PBk, lb, zx);
    lstm_kernel<<<NB, 1024, 0, stream>>>(zx, PF, hseqbf);
    gemm_pir<<<64, 256, 0, stream>>>(hseqbf, PBpir, pirB, vB, a_tk, entpir, ppira, vpred);
    gemm_pim<<<dim3(64, 256), 256, 0, stream>>>(hseqbf, PBpim, pimB, mask, a_tk, partS, partU, za);
    pimfin_gae_kernel<<<17, 256, 0, stream>>>(partS, partU, za, entpim, ppima, gae, scal);
    pg_kernel<<<16, 256, 0, stream>>>(ppira, ppima, entpir, entpim, lgold, gae, scal);
    vf_kernel<<<BT, 256, 0, stream>>>(vpred, ovp, ret, scal);
    fin_kernel<<<1, 1, 0, stream>>>(scal, flag, (u16*)d_out);
}